// Round 8
// baseline (270.825 us; speedup 1.0000x reference)
//
#include <hip/hip_runtime.h>
#include <hip/hip_bf16.h>
#include <math.h>

#define PROJ_EPSF 0.004f
#define MIN_NORMF 1e-15f
#define ATANH_EPSF 1e-5f
#define WEI_EPSF 1e-3f
#define LN2F 0.69314718055994531f

#define TT 1024
#define CC 768
#define HH 12
#define BBATCH 4

typedef unsigned long long ull;
typedef __attribute__((ext_vector_type(4))) float f32x4;
typedef __attribute__((ext_vector_type(8))) short bf16x8;

#define MFMA(a, b, c) __builtin_amdgcn_mfma_f32_16x16x32_bf16(a, b, c, 0, 0, 0)

static __device__ __forceinline__ uint cvtpk(float a, float b) {
    uint r;
    asm("v_cvt_pk_bf16_f32 %0, %1, %2" : "=v"(r) : "v"(a), "v"(b));
    return r;
}
static __device__ __forceinline__ ushort f2bf(float f) {
    uint u = __float_as_uint(f);
    u += 0x7fffu + ((u >> 16) & 1u);
    return (ushort)(u >> 16);
}
static __device__ __forceinline__ float bf2f(ushort h) {
    return __uint_as_float(((uint)h) << 16);
}
static __device__ __forceinline__ void split4(const float4& f, ull& hp, ull& lp) {
    uint h01 = cvtpk(f.x, f.y), h23 = cvtpk(f.z, f.w);
    float r0 = f.x - __uint_as_float(h01 << 16);
    float r1 = f.y - __uint_as_float(h01 & 0xffff0000u);
    float r2 = f.z - __uint_as_float(h23 << 16);
    float r3 = f.w - __uint_as_float(h23 & 0xffff0000u);
    uint l01 = cvtpk(r0, r1), l23 = cvtpk(r2, r3);
    hp = ((ull)h23 << 32) | h01;
    lp = ((ull)l23 << 32) | l01;
}
union pk16 { bf16x8 v; ull u[2]; };

// ---------------- prep: f32 -> bf16 hi/lo planes ----------------
__global__ __launch_bounds__(256) void wprep(const float* __restrict__ W,
                                             ushort* __restrict__ Wh,
                                             ushort* __restrict__ Wl, int n4) {
    int i = blockIdx.x * 256 + threadIdx.x;
    if (i < n4) {
        float4 f = ((const float4*)W)[i];
        ull hp, lp;
        split4(f, hp, lp);
        ((ull*)Wh)[i] = hp;
        ((ull*)Wl)[i] = lp;
    }
}

// ---------------- LDS-free fused QKV GEMM + projection + layout ----------------
// grid (32, 18): blockIdx.x = m-strip (fastest -> B n-tile stays XCD-L2-hot),
// blockIdx.y = n-tile.  All MFMA operands stream from L2 as b128 fragments;
// A (x, f32) is hi/lo-split in registers.  No LDS, no barriers.
__global__ __launch_bounds__(256) void gemm_qkv(
        const float* __restrict__ x, const ushort* __restrict__ Wh,
        const ushort* __restrict__ Wl, const float* __restrict__ kcurv,
        ushort* __restrict__ qh, ushort* __restrict__ ql,
        ushort* __restrict__ kh, ushort* __restrict__ kl,
        ushort* __restrict__ vT, float* __restrict__ x2g,
        float* __restrict__ y2g) {
    const int tid = threadIdx.x, lane = tid & 63, wv = tid >> 6;
    const int wr = wv >> 1, wc = wv & 1, lr = lane & 15, lg = lane >> 4;
    const int m0 = blockIdx.x * 128, n0 = blockIdx.y * 128;
    const bool isV = (n0 >= 2 * CC);

    const float* Ap = x + (size_t)(m0 + wr * 64 + lr) * CC + lg * 8;
    const ushort* Bhp = Wh + (size_t)(n0 + wc * 64 + lr) * CC + lg * 8;
    const ushort* Blp = Wl + (size_t)(n0 + wc * 64 + lr) * CC + lg * 8;

    f32x4 acc[4][4] = {};

    for (int kk = 0; kk < CC; kk += 32) {
        bf16x8 aH[4], aL[4];
#pragma unroll
        for (int m = 0; m < 4; ++m) {
            const float* ap = Ap + (size_t)m * 16 * CC + kk;
            float4 f0 = *(const float4*)(ap);
            float4 f1 = *(const float4*)(ap + 4);
            pk16 h, l;
            split4(f0, h.u[0], l.u[0]);
            split4(f1, h.u[1], l.u[1]);
            aH[m] = h.v;
            aL[m] = l.v;
        }
        if (!isV) {
#pragma unroll
            for (int n = 0; n < 4; ++n) {
                bf16x8 bH = *(const bf16x8*)(Bhp + (size_t)n * 16 * CC + kk);
                bf16x8 bL = *(const bf16x8*)(Blp + (size_t)n * 16 * CC + kk);
#pragma unroll
                for (int m = 0; m < 4; ++m) {
                    acc[m][n] = MFMA(aH[m], bH, acc[m][n]);
                    acc[m][n] = MFMA(aH[m], bL, acc[m][n]);
                    acc[m][n] = MFMA(aL[m], bH, acc[m][n]);
                }
            }
        } else {
#pragma unroll
            for (int n = 0; n < 4; ++n) {
                bf16x8 bH = *(const bf16x8*)(Bhp + (size_t)n * 16 * CC + kk);
                // swapped operands: D rows = W(v)-rows (d), cols = tokens
#pragma unroll
                for (int m = 0; m < 4; ++m)
                    acc[n][m] = MFMA(bH, aH[m], acc[n][m]);
            }
        }
    }
    // ---- epilogue ----
    if (isV) {
        const int hd = (n0 - 2 * CC) / 64 + wc;
#pragma unroll
        for (int n = 0; n < 4; ++n)
#pragma unroll
            for (int m = 0; m < 4; ++m)
#pragma unroll
                for (int r = 0; r < 4; ++r) {
                    const int dl = n * 16 + lg * 4 + r;
                    const int tok = m0 + wr * 64 + m * 16 + lr;
                    vT[(size_t)(hd * 64 + dl) * 4096 + tok] = f2bf(acc[n][m][r]);
                }
    } else {
        const bool isQ = (n0 < CC);
        const int hd = (isQ ? n0 : n0 - CC) / 64 + wc;
        ushort* ph = isQ ? qh : kh;
        ushort* pl = isQ ? ql : kl;
        float* sg = isQ ? x2g : y2g;
        const float kcv = kcurv[hd];
        const float mxn = (1.0f - PROJ_EPSF) / sqrtf(kcv);
        const float mxn2 = mxn * mxn;
#pragma unroll
        for (int m = 0; m < 4; ++m)
#pragma unroll
            for (int r = 0; r < 4; ++r) {
                float s = 0.f;
#pragma unroll
                for (int n = 0; n < 4; ++n) s = fmaf(acc[m][n][r], acc[m][n][r], s);
                s += __shfl_xor(s, 1);
                s += __shfl_xor(s, 2);
                s += __shfl_xor(s, 4);
                s += __shfl_xor(s, 8);
                float scale = 1.0f, x2v = s;
                if (s > mxn2) {
                    scale = mxn * __builtin_amdgcn_rcpf(sqrtf(s));
                    x2v = s * scale * scale;
                }
                const int tok = m0 + wr * 64 + m * 16 + lg * 4 + r;
                const size_t rowb = (size_t)tok * CC + (isQ ? n0 : n0 - CC) + wc * 64;
#pragma unroll
                for (int n = 0; n < 4; ++n) {
                    const float v = acc[m][n][r] * scale;
                    const ushort hb = f2bf(v);
                    ph[rowb + n * 16 + lr] = hb;
                    pl[rowb + n * 16 + lr] = f2bf(v - bf2f(hb));
                }
                if (lr == 0)
                    sg[(size_t)((tok >> 10) * HH + hd) * TT + (tok & 1023)] = x2v;
            }
    }
}

// ---------------- 4-way split-j attention, XCD-localized, PV pipelined ----------------
// PV of tile t-1 runs inside tile t's S-MFMAs: the wt LDS write->read round
// trip is off the critical path (one full iteration of slack).
__global__ __launch_bounds__(256) void hyp_attn(
        const ushort* __restrict__ qh, const ushort* __restrict__ ql,
        const ushort* __restrict__ kh, const ushort* __restrict__ kl,
        const ushort* __restrict__ vT, const float* __restrict__ x2g,
        const float* __restrict__ y2g, const float* __restrict__ kcurv,
        ushort* __restrict__ yh, ushort* __restrict__ yl) {
    const int ib = (int)blockIdx.x;          // 0..3071
    const int xcd = ib & 7, t = ib >> 3;
    const int rg = 63 - (t & 63);            // long blocks first, per XCD
    const int bh = ((t >> 6) << 3) + xcd;    // bh%8 == XCD id
    const int b = bh / HH, h = bh - b * HH;
    const int tid = threadIdx.x, lane = tid & 63, wv = tid >> 6;
    const int lr = lane & 15, lg = lane >> 4;
    const int rgq = rg >> 2;

    __shared__ ushort wt[4][16 * 72];
    __shared__ float cmb[3][16][65];
    __shared__ float dcmb[3][16];
    ushort* wtw = wt[wv];

    const float kc = kcurv[h];
    const float sk = sqrtf(kc);
    const float distc = LN2F / sk;
    const float d2c = distc * distc;
    const float twokc = 2.0f * kc;
    const float cA = 1.0f - ATANH_EPSF;

    const size_t qrb = (size_t)(b * TT + rg * 16 + lr) * CC + h * 64 + lg * 8;
    const bf16x8 qH0 = *(const bf16x8*)(qh + qrb), qH1 = *(const bf16x8*)(qh + qrb + 32);
    const bf16x8 qL0 = *(const bf16x8*)(ql + qrb), qL1 = *(const bf16x8*)(ql + qrb + 32);
    const float4 x2v = *(const float4*)&x2g[(size_t)bh * TT + rg * 16 + lg * 4];
    const float x2a[4] = { x2v.x, x2v.y, x2v.z, x2v.w };
    float kx2[4], Bc[4], Bc2[4];
#pragma unroll
    for (int r = 0; r < 4; ++r) {
        kx2[r] = kc * x2a[r];
        Bc[r] = 1.0f - kx2[r];
        Bc2[r] = Bc[r] * Bc[r];
    }

    f32x4 pv0 = {}, pv1 = {}, pv2 = {}, pv3 = {};
    float wsum[4] = {};

#define TRANSF(NN, SA, Y2R)                                                        \
    {                                                                              \
        const float ky2 = kc * (Y2R);                                              \
        const float p1 = 1.0f + ky2;                                               \
        const int jg = j0 + NN * 16 + lr;                                          \
        _Pragma("unroll") for (int r = 0; r < 4; ++r) {                            \
            const float xy = SA[r];                                                \
            const float t2 = twokc * xy;                                           \
            const float Aa = p1 - t2;                                              \
            const float dn = fmaxf(fmaf(kx2[r], ky2, 1.0f) - t2, MIN_NORMF);       \
            const float ABxy = Aa * (Bc[r] * xy);                                  \
            const float c1 = fmaf(Bc2[r], (Y2R), -2.0f * ABxy);                    \
            const float num2 = fmaf(Aa * Aa, x2a[r], c1);                          \
            const float s = sqrtf(fmaxf(num2, MIN_NORMF));                         \
            const float sm = fminf(sk * s, cA * dn);                               \
            const float L = __builtin_amdgcn_logf((dn + sm) *                      \
                                __builtin_amdgcn_rcpf(dn - sm));                   \
            float w = __builtin_amdgcn_rcpf(fmaf(L * L, d2c, WEI_EPSF));           \
            if (mk && (jg > rg * 16 + lg * 4 + r)) w = 0.0f;                       \
            wtw[(lg * 4 + r) * 72 + NN * 16 + lr] = f2bf(w);                       \
            wsum[r] += w;                                                          \
        }                                                                          \
    }

#define LOADG2(KH, KL, BASE)                                                       \
    KH[0] = *(const bf16x8*)(kh + (BASE));                                         \
    KH[1] = *(const bf16x8*)(kh + (BASE) + 32);                                    \
    KL[0] = *(const bf16x8*)(kl + (BASE));                                         \
    KL[1] = *(const bf16x8*)(kl + (BASE) + 32);

#define LOADV(J0)                                                                  \
    _Pragma("unroll") for (int n = 0; n < 4; ++n) {                                \
        const size_t vb = (size_t)(h * 64 + n * 16 + lr) * 4096 + b * TT + (J0) + lg * 8; \
        vF[n][0] = *(const bf16x8*)(vT + vb);                                      \
        vF[n][1] = *(const bf16x8*)(vT + vb + 32);                                 \
    }

#define PVALL                                                                      \
    pv0 = MFMA(pw0, vF[0][0], pv0); pv0 = MFMA(pw1, vF[0][1], pv0);                \
    pv1 = MFMA(pw0, vF[1][0], pv1); pv1 = MFMA(pw1, vF[1][1], pv1);                \
    pv2 = MFMA(pw0, vF[2][0], pv2); pv2 = MFMA(pw1, vF[2][1], pv2);                \
    pv3 = MFMA(pw0, vF[3][0], pv3); pv3 = MFMA(pw1, vF[3][1], pv3);

#define MMG(SA, KH, KL)                                                            \
    SA = MFMA(qH0, KH[0], SA); SA = MFMA(qH0, KL[0], SA); SA = MFMA(qL0, KH[0], SA); \
    SA = MFMA(qH1, KH[1], SA); SA = MFMA(qH1, KL[1], SA); SA = MFMA(qL1, KH[1], SA);

    size_t kbase = (size_t)(b * TT + wv * 64 + lr) * CC + h * 64 + lg * 8;
    bf16x8 kH0[2], kL0[2], kH1[2], kL1[2], kH2[2], kL2[2], kH3[2], kL3[2];
    if (wv <= rgq) {
        LOADG2(kH0, kL0, kbase)
        LOADG2(kH1, kL1, kbase + 16 * CC)
    }

    int j0p = -1;   // previous tile's j0 (PV pending)
    for (int jt = wv; jt <= rgq; jt += 4) {
        const int j0 = jt * 64;
        const bool mk = (jt == rgq);
        __builtin_amdgcn_s_setprio(1);
        // ---- prev-tile PV operands: fetch early (LDS round trip hidden) ----
        bf16x8 pw0, pw1, vF[4][2];
        if (j0p >= 0) {
            pw0 = *(const bf16x8*)&wtw[lr * 72 + lg * 8];
            pw1 = *(const bf16x8*)&wtw[lr * 72 + 32 + lg * 8];
            LOADV(j0p)
        }
        const size_t y2b = (size_t)bh * TT + j0 + lr;
        const float y20 = y2g[y2b], y21 = y2g[y2b + 16];
        const float y22 = y2g[y2b + 32], y23 = y2g[y2b + 48];
        f32x4 s0 = {}, s1 = {}, s2 = {}, s3 = {};
        MMG(s0, kH0, kL0)
        LOADG2(kH2, kL2, kbase + 32 * CC)
        MMG(s1, kH1, kL1)
        LOADG2(kH3, kL3, kbase + 48 * CC)
        if (j0p >= 0) { PVALL }
        MMG(s2, kH2, kL2)
        MMG(s3, kH3, kL3)
        // prefetch next tile's first two K groups (hidden under transform)
        kbase += (size_t)256 * CC;
        if (jt + 4 <= rgq) {
            LOADG2(kH0, kL0, kbase)
            LOADG2(kH1, kL1, kbase + 16 * CC)
        }
        TRANSF(0, s0, y20)
        TRANSF(1, s1, y21)
        TRANSF(2, s2, y22)
        TRANSF(3, s3, y23)
        __builtin_amdgcn_s_setprio(0);
        j0p = j0;
    }
    // ---- drain: PV of the final tile ----
    if (j0p >= 0) {
        bf16x8 pw0, pw1, vF[4][2];
        pw0 = *(const bf16x8*)&wtw[lr * 72 + lg * 8];
        pw1 = *(const bf16x8*)&wtw[lr * 72 + 32 + lg * 8];
        LOADV(j0p)
        PVALL
    }

    // ---- reduce den over lr lanes ----
    float den[4];
#pragma unroll
    for (int r = 0; r < 4; ++r) {
        float s = wsum[r];
        s += __shfl_xor(s, 1);
        s += __shfl_xor(s, 2);
        s += __shfl_xor(s, 4);
        s += __shfl_xor(s, 8);
        den[r] = s;
    }
    // ---- combine partials across the 4 waves ----
    if (wv > 0) {
#pragma unroll
        for (int r = 0; r < 4; ++r) {
            cmb[wv - 1][lg * 4 + r][0 * 16 + lr] = pv0[r];
            cmb[wv - 1][lg * 4 + r][1 * 16 + lr] = pv1[r];
            cmb[wv - 1][lg * 4 + r][2 * 16 + lr] = pv2[r];
            cmb[wv - 1][lg * 4 + r][3 * 16 + lr] = pv3[r];
        }
        if (lr == 0)
#pragma unroll
            for (int r = 0; r < 4; ++r) dcmb[wv - 1][lg * 4 + r] = den[r];
    }
    __syncthreads();
    if (wv == 0) {
        f32x4* pvp[4] = { &pv0, &pv1, &pv2, &pv3 };
#pragma unroll
        for (int r = 0; r < 4; ++r) {
            const int il = lg * 4 + r;
            const float dt = den[r] + dcmb[0][il] + dcmb[1][il] + dcmb[2][il];
            const float iv = __builtin_amdgcn_rcpf(dt);
            const size_t rowb = (size_t)(b * TT + rg * 16 + il) * CC + h * 64;
#pragma unroll
            for (int n = 0; n < 4; ++n) {
                const float val = ((*pvp[n])[r] + cmb[0][il][n * 16 + lr] +
                                   cmb[1][il][n * 16 + lr] + cmb[2][il][n * 16 + lr]) * iv;
                const ushort hb = f2bf(val);
                yh[rowb + n * 16 + lr] = hb;
                yl[rowb + n * 16 + lr] = f2bf(val - bf2f(hb));
            }
        }
    }
#undef TRANSF
#undef LOADG2
#undef LOADV
#undef PVALL
#undef MMG
}

// ---------------- LDS-free output GEMM: out = y @ Wproj^T ----------------
// grid (32, 6): m fastest; operands stream from L2 as b128 fragments.
__global__ __launch_bounds__(256) void gemm_out(const ushort* __restrict__ Ahp,
                                                const ushort* __restrict__ Alp,
                                                const ushort* __restrict__ Wh,
                                                const ushort* __restrict__ Wl,
                                                float* __restrict__ C) {
    const int tid = threadIdx.x, lane = tid & 63, wv = tid >> 6;
    const int wr = wv >> 1, wc = wv & 1, lr = lane & 15, lg = lane >> 4;
    const int m0 = blockIdx.x * 128, n0 = blockIdx.y * 128;

    const ushort* Ahq = Ahp + (size_t)(m0 + wr * 64 + lr) * CC + lg * 8;
    const ushort* Alq = Alp + (size_t)(m0 + wr * 64 + lr) * CC + lg * 8;
    const ushort* Bhp = Wh + (size_t)(n0 + wc * 64 + lr) * CC + lg * 8;
    const ushort* Blp = Wl + (size_t)(n0 + wc * 64 + lr) * CC + lg * 8;

    f32x4 acc[4][4] = {};

    for (int kk = 0; kk < CC; kk += 32) {
        bf16x8 aH[4], aL[4];
#pragma unroll
        for (int m = 0; m < 4; ++m) {
            aH[m] = *(const bf16x8*)(Ahq + (size_t)m * 16 * CC + kk);
            aL[m] = *(const bf16x8*)(Alq + (size_t)m * 16 * CC + kk);
        }
#pragma unroll
        for (int n = 0; n < 4; ++n) {
            bf16x8 bH = *(const bf16x8*)(Bhp + (size_t)n * 16 * CC + kk);
            bf16x8 bL = *(const bf16x8*)(Blp + (size_t)n * 16 * CC + kk);
#pragma unroll
            for (int m = 0; m < 4; ++m) {
                acc[m][n] = MFMA(aH[m], bH, acc[m][n]);
                acc[m][n] = MFMA(aH[m], bL, acc[m][n]);
                acc[m][n] = MFMA(aL[m], bH, acc[m][n]);
            }
        }
    }
#pragma unroll
    for (int m = 0; m < 4; ++m)
#pragma unroll
        for (int n = 0; n < 4; ++n)
#pragma unroll
            for (int r = 0; r < 4; ++r)
                C[(size_t)(m0 + wr * 64 + m * 16 + lg * 4 + r) * CC + n0 + wc * 64 + n * 16 + lr] =
                    acc[m][n][r];
}

extern "C" void kernel_launch(void* const* d_in, const int* in_sizes, int n_in,
                              void* d_out, int out_size, void* d_ws, size_t ws_size,
                              hipStream_t stream) {
    const float* x     = (const float*)d_in[0];
    const float* Wqkv  = (const float*)d_in[1];
    const float* Wproj = (const float*)d_in[2];
    const float* kcurv = (const float*)d_in[3];
    float* out = (float*)d_out;

    const size_t PL = (size_t)4096 * CC;          // 3,145,728 elems
    char* w = (char*)d_ws;
    // region A (12.58 MB): Wqkv hi/lo planes during gemm_qkv; yh/yl after attn
    ushort* Wqh = (ushort*)w;                     // 3.54 MB
    ushort* Wql = Wqh + (size_t)2304 * CC;        // 3.54 MB
    ushort* yh  = (ushort*)w;                     // 6.29 MB (reuse)
    ushort* yl  = yh + PL;                        // 6.29 MB
    ushort* qh  = (ushort*)(w + 2 * PL * 2);      // planes: 5 x 6.29 MB
    ushort* ql  = qh + PL;
    ushort* kh  = ql + PL;
    ushort* kl  = kh + PL;
    ushort* vT  = kl + PL;                        // [12][64][4096]
    ushort* Wph = vT + PL;                        // 1.18 MB
    ushort* Wpl = Wph + (size_t)CC * CC;          // 1.18 MB
    float* x2g  = (float*)(Wpl + (size_t)CC * CC);   // [4][12][1024]
    float* y2g  = x2g + 48 * TT;
    // total: 46,792,704 B

    wprep<<<2304 * CC / 4 / 256, 256, 0, stream>>>(Wqkv, Wqh, Wql, 2304 * CC / 4);
    wprep<<<CC * CC / 4 / 256, 256, 0, stream>>>(Wproj, Wph, Wpl, CC * CC / 4);
    gemm_qkv<<<dim3(32, 18), 256, 0, stream>>>(x, Wqh, Wql, kcurv,
                                               qh, ql, kh, kl, vT, x2g, y2g);
    hyp_attn<<<3072, 256, 0, stream>>>(qh, ql, kh, kl, vT, x2g, y2g, kcurv, yh, yl);
    gemm_out<<<dim3(32, 6), 256, 0, stream>>>(yh, yl, Wph, Wpl, out);
}

// Round 9
// 217.612 us; speedup vs baseline: 1.2445x; 1.2445x over previous
//
#include <hip/hip_runtime.h>
#include <hip/hip_bf16.h>
#include <math.h>

#define PROJ_EPSF 0.004f
#define MIN_NORMF 1e-15f
#define ATANH_EPSF 1e-5f
#define WEI_EPSF 1e-3f
#define LN2F 0.69314718055994531f

#define TT 1024
#define CC 768
#define HH 12
#define BBATCH 4

typedef unsigned long long ull;
typedef __attribute__((ext_vector_type(4))) float f32x4;
typedef __attribute__((ext_vector_type(8))) short bf16x8;

#define MFMA(a, b, c) __builtin_amdgcn_mfma_f32_16x16x32_bf16(a, b, c, 0, 0, 0)

static __device__ __forceinline__ uint cvtpk(float a, float b) {
    uint r;
    asm("v_cvt_pk_bf16_f32 %0, %1, %2" : "=v"(r) : "v"(a), "v"(b));
    return r;
}
static __device__ __forceinline__ ushort f2bf(float f) {
    uint u = __float_as_uint(f);
    u += 0x7fffu + ((u >> 16) & 1u);
    return (ushort)(u >> 16);
}
static __device__ __forceinline__ float bf2f(ushort h) {
    return __uint_as_float(((uint)h) << 16);
}
static __device__ __forceinline__ void split4(const float4& f, ull& hp, ull& lp) {
    uint h01 = cvtpk(f.x, f.y), h23 = cvtpk(f.z, f.w);
    float r0 = f.x - __uint_as_float(h01 << 16);
    float r1 = f.y - __uint_as_float(h01 & 0xffff0000u);
    float r2 = f.z - __uint_as_float(h23 << 16);
    float r3 = f.w - __uint_as_float(h23 & 0xffff0000u);
    uint l01 = cvtpk(r0, r1), l23 = cvtpk(r2, r3);
    hp = ((ull)h23 << 32) | h01;
    lp = ((ull)l23 << 32) | l01;
}

// ---------------- prep: f32 -> bf16 hi/lo planes ----------------
__global__ __launch_bounds__(256) void wprep(const float* __restrict__ W,
                                             ushort* __restrict__ Wh,
                                             ushort* __restrict__ Wl, int n4) {
    int i = blockIdx.x * 256 + threadIdx.x;
    if (i < n4) {
        float4 f = ((const float4*)W)[i];
        ull hp, lp;
        split4(f, hp, lp);
        ((ull*)Wh)[i] = hp;
        ((ull*)Wl)[i] = lp;
    }
}

// ---------------- fused QKV GEMM + Poincare projection + layout ----------------
template <bool PS>
__global__ __launch_bounds__(256) void gemm_qkv(
        const float* __restrict__ xf, const ushort* __restrict__ xhp,
        const ushort* __restrict__ xlp, const ushort* __restrict__ Wh,
        const ushort* __restrict__ Wl, const float* __restrict__ kcurv,
        ushort* __restrict__ qh, ushort* __restrict__ ql,
        ushort* __restrict__ kh, ushort* __restrict__ kl,
        ushort* __restrict__ vT, float* __restrict__ x2g,
        float* __restrict__ y2g) {
    __shared__ ushort Ah[128 * 40], Al[128 * 40], Bh[128 * 40], Bl[128 * 40];
    const int tid = threadIdx.x, lane = tid & 63, wv = tid >> 6;
    const int wr = wv >> 1, wc = wv & 1, lr = lane & 15, lg = lane >> 4;
    const int m0 = blockIdx.y * 128, n0 = blockIdx.x * 128;
    const bool isV = (n0 >= 2 * CC);
    const int srow = tid >> 1, sk0 = (tid & 1) * 16;
    const float* Ap = xf + (size_t)(m0 + srow) * CC + sk0;
    const ushort* Axh = xhp + (size_t)(m0 + srow) * CC + sk0;
    const ushort* Axl = xlp + (size_t)(m0 + srow) * CC + sk0;
    const ushort* Bhp = Wh + (size_t)(n0 + srow) * CC + sk0;
    const ushort* Blp = Wl + (size_t)(n0 + srow) * CC + sk0;

    f32x4 acc[4][4] = {};
    float4 av[4];
    bf16x8 ahv[2], alv[2], bhv[2], blv[2];
    if constexpr (PS) {
        ahv[0] = *(const bf16x8*)(Axh);
        ahv[1] = *(const bf16x8*)(Axh + 8);
        if (!isV) {
            alv[0] = *(const bf16x8*)(Axl);
            alv[1] = *(const bf16x8*)(Axl + 8);
        }
    } else {
#pragma unroll
        for (int q = 0; q < 4; ++q) av[q] = *(const float4*)(Ap + 4 * q);
    }
    bhv[0] = *(const bf16x8*)(Bhp);
    bhv[1] = *(const bf16x8*)(Bhp + 8);
    if (!isV) {
        blv[0] = *(const bf16x8*)(Blp);
        blv[1] = *(const bf16x8*)(Blp + 8);
    }

    for (int kk = 0; kk < CC; kk += 32) {
        __syncthreads();
        if constexpr (PS) {
            *(bf16x8*)&Ah[srow * 40 + sk0] = ahv[0];
            *(bf16x8*)&Ah[srow * 40 + sk0 + 8] = ahv[1];
            if (!isV) {
                *(bf16x8*)&Al[srow * 40 + sk0] = alv[0];
                *(bf16x8*)&Al[srow * 40 + sk0 + 8] = alv[1];
            }
        } else {
#pragma unroll
            for (int q = 0; q < 4; ++q) {
                ull hp, lp;
                split4(av[q], hp, lp);
                *(ull*)&Ah[srow * 40 + sk0 + 4 * q] = hp;
                if (!isV) *(ull*)&Al[srow * 40 + sk0 + 4 * q] = lp;
            }
        }
        *(bf16x8*)&Bh[srow * 40 + sk0] = bhv[0];
        *(bf16x8*)&Bh[srow * 40 + sk0 + 8] = bhv[1];
        if (!isV) {
            *(bf16x8*)&Bl[srow * 40 + sk0] = blv[0];
            *(bf16x8*)&Bl[srow * 40 + sk0 + 8] = blv[1];
        }
        __syncthreads();
        if (kk + 32 < CC) {
            if constexpr (PS) {
                ahv[0] = *(const bf16x8*)(Axh + kk + 32);
                ahv[1] = *(const bf16x8*)(Axh + kk + 40);
                if (!isV) {
                    alv[0] = *(const bf16x8*)(Axl + kk + 32);
                    alv[1] = *(const bf16x8*)(Axl + kk + 40);
                }
            } else {
#pragma unroll
                for (int q = 0; q < 4; ++q)
                    av[q] = *(const float4*)(Ap + kk + 32 + 4 * q);
            }
            bhv[0] = *(const bf16x8*)(Bhp + kk + 32);
            bhv[1] = *(const bf16x8*)(Bhp + kk + 40);
            if (!isV) {
                blv[0] = *(const bf16x8*)(Blp + kk + 32);
                blv[1] = *(const bf16x8*)(Blp + kk + 40);
            }
        }
        if (!isV) {
            bf16x8 a_h[4], a_l[4];
#pragma unroll
            for (int m = 0; m < 4; ++m) {
                const int off = (wr * 64 + m * 16 + lr) * 40 + lg * 8;
                a_h[m] = *(const bf16x8*)&Ah[off];
                a_l[m] = *(const bf16x8*)&Al[off];
            }
#pragma unroll
            for (int n = 0; n < 4; ++n) {
                const int off = (wc * 64 + n * 16 + lr) * 40 + lg * 8;
                bf16x8 b_h = *(const bf16x8*)&Bh[off];
                bf16x8 b_l = *(const bf16x8*)&Bl[off];
#pragma unroll
                for (int m = 0; m < 4; ++m) {
                    acc[m][n] = MFMA(a_h[m], b_h, acc[m][n]);
                    acc[m][n] = MFMA(a_h[m], b_l, acc[m][n]);
                    acc[m][n] = MFMA(a_l[m], b_h, acc[m][n]);
                }
            }
        } else {
            bf16x8 a_h[4], b_h[4];
#pragma unroll
            for (int m = 0; m < 4; ++m)
                a_h[m] = *(const bf16x8*)&Ah[(wr * 64 + m * 16 + lr) * 40 + lg * 8];
#pragma unroll
            for (int n = 0; n < 4; ++n)
                b_h[n] = *(const bf16x8*)&Bh[(wc * 64 + n * 16 + lr) * 40 + lg * 8];
#pragma unroll
            for (int n = 0; n < 4; ++n)
#pragma unroll
                for (int m = 0; m < 4; ++m)
                    acc[n][m] = MFMA(b_h[n], a_h[m], acc[n][m]);
        }
    }
    // ---- epilogue ----
    if (isV) {
        const int hd = (n0 - 2 * CC) / 64 + wc;
#pragma unroll
        for (int n = 0; n < 4; ++n)
#pragma unroll
            for (int m = 0; m < 4; ++m)
#pragma unroll
                for (int r = 0; r < 4; ++r) {
                    const int dl = n * 16 + lg * 4 + r;
                    const int tok = m0 + wr * 64 + m * 16 + lr;
                    vT[(size_t)(hd * 64 + dl) * 4096 + tok] = f2bf(acc[n][m][r]);
                }
    } else {
        const bool isQ = (n0 < CC);
        const int hd = (isQ ? n0 : n0 - CC) / 64 + wc;
        ushort* ph = isQ ? qh : kh;
        ushort* pl = isQ ? ql : kl;
        float* sg = isQ ? x2g : y2g;
        const float kcv = kcurv[hd];
        const float mxn = (1.0f - PROJ_EPSF) / sqrtf(kcv);
        const float mxn2 = mxn * mxn;
#pragma unroll
        for (int m = 0; m < 4; ++m)
#pragma unroll
            for (int r = 0; r < 4; ++r) {
                float s = 0.f;
#pragma unroll
                for (int n = 0; n < 4; ++n) s = fmaf(acc[m][n][r], acc[m][n][r], s);
                s += __shfl_xor(s, 1);
                s += __shfl_xor(s, 2);
                s += __shfl_xor(s, 4);
                s += __shfl_xor(s, 8);
                float scale = 1.0f, x2v = s;
                if (s > mxn2) {
                    scale = mxn * __builtin_amdgcn_rcpf(sqrtf(s));
                    x2v = s * scale * scale;
                }
                const int tok = m0 + wr * 64 + m * 16 + lg * 4 + r;
                const size_t rowb = (size_t)tok * CC + (isQ ? n0 : n0 - CC) + wc * 64;
#pragma unroll
                for (int n = 0; n < 4; ++n) {
                    const float v = acc[m][n][r] * scale;
                    const ushort hb = f2bf(v);
                    ph[rowb + n * 16 + lr] = hb;
                    pl[rowb + n * 16 + lr] = f2bf(v - bf2f(hb));
                }
                if (lr == 0)
                    sg[(size_t)((tok >> 10) * HH + hd) * TT + (tok & 1023)] = x2v;
            }
    }
}

// ---------------- paired 8-wave split-j attention, XCD-localized ----------------
// Block = row-group pair (pA, 63-pA): uniform ~17 tiles / 8 waves.
// Each rg handled by 4 waves (j-split); per-rg combine in LDS.
__global__ __launch_bounds__(512) void hyp_attn(
        const ushort* __restrict__ qh, const ushort* __restrict__ ql,
        const ushort* __restrict__ kh, const ushort* __restrict__ kl,
        const ushort* __restrict__ vT, const float* __restrict__ x2g,
        const float* __restrict__ y2g, const float* __restrict__ kcurv,
        ushort* __restrict__ yh, ushort* __restrict__ yl) {
    const int ib = (int)blockIdx.x;          // 0..1535
    const int xcd = ib & 7, t = ib >> 3;     // t 0..191
    const int pA = t & 31;                   // pair id
    const int bh = ((t >> 5) << 3) + xcd;    // bh%8 == XCD id
    const int b = bh / HH, h = bh - b * HH;
    const int tid = threadIdx.x, lane = tid & 63, wv = tid >> 6;   // wv 0..7
    const int half = wv >> 2, sub = wv & 3;
    const int lr = lane & 15, lg = lane >> 4;
    const int rg = half ? (63 - pA) : pA;    // 16-row group
    const int rgq = rg >> 2;

    __shared__ ushort wt[8][16 * 72];
    __shared__ float cmb[2][3][16][65];
    __shared__ float dcmb[2][3][16];
    ushort* wtw = wt[wv];

    const float kc = kcurv[h];
    const float sk = sqrtf(kc);
    const float distc = LN2F / sk;
    const float d2c = distc * distc;
    const float twokc = 2.0f * kc;
    const float cA = 1.0f - ATANH_EPSF;

    const size_t qrb = (size_t)(b * TT + rg * 16 + lr) * CC + h * 64 + lg * 8;
    const bf16x8 qH0 = *(const bf16x8*)(qh + qrb), qH1 = *(const bf16x8*)(qh + qrb + 32);
    const bf16x8 qL0 = *(const bf16x8*)(ql + qrb), qL1 = *(const bf16x8*)(ql + qrb + 32);
    const float4 x2v = *(const float4*)&x2g[(size_t)bh * TT + rg * 16 + lg * 4];
    const float x2a[4] = { x2v.x, x2v.y, x2v.z, x2v.w };
    float kx2[4], Bc[4], Bc2[4];
#pragma unroll
    for (int r = 0; r < 4; ++r) {
        kx2[r] = kc * x2a[r];
        Bc[r] = 1.0f - kx2[r];
        Bc2[r] = Bc[r] * Bc[r];
    }

    f32x4 pv0 = {}, pv1 = {}, pv2 = {}, pv3 = {};
    float wsum[4] = {};

#define TRANSF(NN, SA, Y2R)                                                        \
    {                                                                              \
        const float ky2 = kc * (Y2R);                                              \
        const float p1 = 1.0f + ky2;                                               \
        const int jg = j0 + NN * 16 + lr;                                          \
        _Pragma("unroll") for (int r = 0; r < 4; ++r) {                            \
            const float xy = SA[r];                                                \
            const float t2 = twokc * xy;                                           \
            const float Aa = p1 - t2;                                              \
            const float dn = fmaxf(fmaf(kx2[r], ky2, 1.0f) - t2, MIN_NORMF);       \
            const float ABxy = Aa * (Bc[r] * xy);                                  \
            const float c1 = fmaf(Bc2[r], (Y2R), -2.0f * ABxy);                    \
            const float num2 = fmaf(Aa * Aa, x2a[r], c1);                          \
            const float s = sqrtf(fmaxf(num2, MIN_NORMF));                         \
            const float sm = fminf(sk * s, cA * dn);                               \
            const float L = __builtin_amdgcn_logf((dn + sm) *                      \
                                __builtin_amdgcn_rcpf(dn - sm));                   \
            float w = __builtin_amdgcn_rcpf(fmaf(L * L, d2c, WEI_EPSF));           \
            if (mk && (jg > rg * 16 + lg * 4 + r)) w = 0.0f;                       \
            wtw[(lg * 4 + r) * 72 + NN * 16 + lr] = f2bf(w);                       \
            wsum[r] += w;                                                          \
        }                                                                          \
    }

#define LOADG2(KH, KL, BASE)                                                       \
    KH[0] = *(const bf16x8*)(kh + (BASE));                                         \
    KH[1] = *(const bf16x8*)(kh + (BASE) + 32);                                    \
    KL[0] = *(const bf16x8*)(kl + (BASE));                                         \
    KL[1] = *(const bf16x8*)(kl + (BASE) + 32);

#define MMG(SA, KH, KL)                                                            \
    SA = MFMA(qH0, KH[0], SA); SA = MFMA(qH0, KL[0], SA); SA = MFMA(qL0, KH[0], SA); \
    SA = MFMA(qH1, KH[1], SA); SA = MFMA(qH1, KL[1], SA); SA = MFMA(qL1, KH[1], SA);

    size_t kbase = (size_t)(b * TT + sub * 64 + lr) * CC + h * 64 + lg * 8;
    bf16x8 kH0[2], kL0[2], kH1[2], kL1[2], kH2[2], kL2[2], kH3[2], kL3[2];
    if (sub <= rgq) {
        LOADG2(kH0, kL0, kbase)
        LOADG2(kH1, kL1, kbase + 16 * CC)
    }

    for (int jt = sub; jt <= rgq; jt += 4) {
        const int j0 = jt * 64;
        const bool mk = (jt == rgq);
        const size_t y2b = (size_t)bh * TT + j0 + lr;
        const float y20 = y2g[y2b], y21 = y2g[y2b + 16];
        const float y22 = y2g[y2b + 32], y23 = y2g[y2b + 48];
        f32x4 s0 = {}, s1 = {}, s2 = {}, s3 = {};
        __builtin_amdgcn_s_setprio(1);
        MMG(s0, kH0, kL0)
        LOADG2(kH2, kL2, kbase + 32 * CC)
        TRANSF(0, s0, y20)
        MMG(s1, kH1, kL1)
        LOADG2(kH3, kL3, kbase + 48 * CC)
        TRANSF(1, s1, y21)
        MMG(s2, kH2, kL2)
        // V fragments: in flight during transforms 2,3
        bf16x8 vF[4][2];
#pragma unroll
        for (int n = 0; n < 4; ++n) {
            const size_t vb = (size_t)(h * 64 + n * 16 + lr) * 4096 + b * TT + j0 + lg * 8;
            vF[n][0] = *(const bf16x8*)(vT + vb);
            vF[n][1] = *(const bf16x8*)(vT + vb + 32);
        }
        TRANSF(2, s2, y22)
        MMG(s3, kH3, kL3)
        TRANSF(3, s3, y23)
        // prefetch next tile's first two K groups during PV
        kbase += (size_t)256 * CC;
        if (jt + 4 <= rgq) {
            LOADG2(kH0, kL0, kbase)
            LOADG2(kH1, kL1, kbase + 16 * CC)
        }
        // ---- PV ----
        bf16x8 pw0 = *(const bf16x8*)&wtw[lr * 72 + lg * 8];
        bf16x8 pw1 = *(const bf16x8*)&wtw[lr * 72 + 32 + lg * 8];
        pv0 = MFMA(pw0, vF[0][0], pv0); pv0 = MFMA(pw1, vF[0][1], pv0);
        pv1 = MFMA(pw0, vF[1][0], pv1); pv1 = MFMA(pw1, vF[1][1], pv1);
        pv2 = MFMA(pw0, vF[2][0], pv2); pv2 = MFMA(pw1, vF[2][1], pv2);
        pv3 = MFMA(pw0, vF[3][0], pv3); pv3 = MFMA(pw1, vF[3][1], pv3);
        __builtin_amdgcn_s_setprio(0);
    }

    // ---- reduce den over lr lanes ----
    float den[4];
#pragma unroll
    for (int r = 0; r < 4; ++r) {
        float s = wsum[r];
        s += __shfl_xor(s, 1);
        s += __shfl_xor(s, 2);
        s += __shfl_xor(s, 4);
        s += __shfl_xor(s, 8);
        den[r] = s;
    }
    // ---- combine partials across the 4 waves of each half ----
    if (sub > 0) {
#pragma unroll
        for (int r = 0; r < 4; ++r) {
            cmb[half][sub - 1][lg * 4 + r][0 * 16 + lr] = pv0[r];
            cmb[half][sub - 1][lg * 4 + r][1 * 16 + lr] = pv1[r];
            cmb[half][sub - 1][lg * 4 + r][2 * 16 + lr] = pv2[r];
            cmb[half][sub - 1][lg * 4 + r][3 * 16 + lr] = pv3[r];
        }
        if (lr == 0)
#pragma unroll
            for (int r = 0; r < 4; ++r) dcmb[half][sub - 1][lg * 4 + r] = den[r];
    }
    __syncthreads();
    if (sub == 0) {
        f32x4* pvp[4] = { &pv0, &pv1, &pv2, &pv3 };
#pragma unroll
        for (int r = 0; r < 4; ++r) {
            const int il = lg * 4 + r;
            const float dt = den[r] + dcmb[half][0][il] + dcmb[half][1][il] + dcmb[half][2][il];
            const float iv = __builtin_amdgcn_rcpf(dt);
            const size_t rowb = (size_t)(b * TT + rg * 16 + il) * CC + h * 64;
#pragma unroll
            for (int n = 0; n < 4; ++n) {
                const float val = ((*pvp[n])[r] + cmb[half][0][il][n * 16 + lr] +
                                   cmb[half][1][il][n * 16 + lr] +
                                   cmb[half][2][il][n * 16 + lr]) * iv;
                const ushort hb = f2bf(val);
                yh[rowb + n * 16 + lr] = hb;
                yl[rowb + n * 16 + lr] = f2bf(val - bf2f(hb));
            }
        }
    }
#undef TRANSF
#undef LOADG2
#undef MMG
}

// ---------------- output GEMM: out = y @ Wproj^T (pre-split A and B) ----------------
__global__ __launch_bounds__(256) void gemm_out(const ushort* __restrict__ Ahp,
                                                const ushort* __restrict__ Alp,
                                                const ushort* __restrict__ Wh,
                                                const ushort* __restrict__ Wl,
                                                float* __restrict__ C) {
    __shared__ ushort Ah[128 * 40], Al[128 * 40], Bh[128 * 40], Bl[128 * 40];
    const int tid = threadIdx.x, lane = tid & 63, wv = tid >> 6;
    const int wr = wv >> 1, wc = wv & 1, lr = lane & 15, lg = lane >> 4;
    const int m0 = blockIdx.y * 128, n0 = blockIdx.x * 128;
    const int srow = tid >> 1, sk0 = (tid & 1) * 16;
    const ushort* Ahq = Ahp + (size_t)(m0 + srow) * CC + sk0;
    const ushort* Alq = Alp + (size_t)(m0 + srow) * CC + sk0;
    const ushort* Bhp = Wh + (size_t)(n0 + srow) * CC + sk0;
    const ushort* Blp = Wl + (size_t)(n0 + srow) * CC + sk0;

    f32x4 acc[4][4] = {};
    bf16x8 ahv[2], alv[2], bhv[2], blv[2];
    ahv[0] = *(const bf16x8*)(Ahq);      ahv[1] = *(const bf16x8*)(Ahq + 8);
    alv[0] = *(const bf16x8*)(Alq);      alv[1] = *(const bf16x8*)(Alq + 8);
    bhv[0] = *(const bf16x8*)(Bhp);      bhv[1] = *(const bf16x8*)(Bhp + 8);
    blv[0] = *(const bf16x8*)(Blp);      blv[1] = *(const bf16x8*)(Blp + 8);

    for (int kk = 0; kk < CC; kk += 32) {
        __syncthreads();
        *(bf16x8*)&Ah[srow * 40 + sk0] = ahv[0];
        *(bf16x8*)&Ah[srow * 40 + sk0 + 8] = ahv[1];
        *(bf16x8*)&Al[srow * 40 + sk0] = alv[0];
        *(bf16x8*)&Al[srow * 40 + sk0 + 8] = alv[1];
        *(bf16x8*)&Bh[srow * 40 + sk0] = bhv[0];
        *(bf16x8*)&Bh[srow * 40 + sk0 + 8] = bhv[1];
        *(bf16x8*)&Bl[srow * 40 + sk0] = blv[0];
        *(bf16x8*)&Bl[srow * 40 + sk0 + 8] = blv[1];
        __syncthreads();
        if (kk + 32 < CC) {
            ahv[0] = *(const bf16x8*)(Ahq + kk + 32);
            ahv[1] = *(const bf16x8*)(Ahq + kk + 40);
            alv[0] = *(const bf16x8*)(Alq + kk + 32);
            alv[1] = *(const bf16x8*)(Alq + kk + 40);
            bhv[0] = *(const bf16x8*)(Bhp + kk + 32);
            bhv[1] = *(const bf16x8*)(Bhp + kk + 40);
            blv[0] = *(const bf16x8*)(Blp + kk + 32);
            blv[1] = *(const bf16x8*)(Blp + kk + 40);
        }
        bf16x8 a_h[4], a_l[4];
#pragma unroll
        for (int m = 0; m < 4; ++m) {
            const int off = (wr * 64 + m * 16 + lr) * 40 + lg * 8;
            a_h[m] = *(const bf16x8*)&Ah[off];
            a_l[m] = *(const bf16x8*)&Al[off];
        }
#pragma unroll
        for (int n = 0; n < 4; ++n) {
            const int off = (wc * 64 + n * 16 + lr) * 40 + lg * 8;
            bf16x8 b_h = *(const bf16x8*)&Bh[off];
            bf16x8 b_l = *(const bf16x8*)&Bl[off];
#pragma unroll
            for (int m = 0; m < 4; ++m) {
                acc[m][n] = MFMA(a_h[m], b_h, acc[m][n]);
                acc[m][n] = MFMA(a_h[m], b_l, acc[m][n]);
                acc[m][n] = MFMA(a_l[m], b_h, acc[m][n]);
            }
        }
    }
#pragma unroll
    for (int m = 0; m < 4; ++m)
#pragma unroll
        for (int n = 0; n < 4; ++n)
#pragma unroll
            for (int r = 0; r < 4; ++r)
                C[(size_t)(m0 + wr * 64 + m * 16 + lg * 4 + r) * CC + n0 + wc * 64 + n * 16 + lr] =
                    acc[m][n][r];
}

extern "C" void kernel_launch(void* const* d_in, const int* in_sizes, int n_in,
                              void* d_out, int out_size, void* d_ws, size_t ws_size,
                              hipStream_t stream) {
    const float* x     = (const float*)d_in[0];
    const float* Wqkv  = (const float*)d_in[1];
    const float* Wproj = (const float*)d_in[2];
    const float* kcurv = (const float*)d_in[3];
    float* out = (float*)d_out;

    const size_t PL = (size_t)4096 * CC;
    char* w = (char*)d_ws;
    const bool ps = ws_size >= 53870592ULL;

    ushort *xh, *xl, *qh, *ql, *kh, *kl, *vT, *Wqh, *Wql, *Wph, *Wpl, *yh, *yl;
    float *x2g, *y2g;
    if (ps) {
        xh = (ushort*)w;          xl = xh + PL;     // reused as yh/yl later
        qh = xl + PL;  ql = qh + PL;  kh = ql + PL;  kl = kh + PL;  vT = kl + PL;
        x2g = (float*)(vT + PL);  y2g = x2g + 48 * TT;
        Wqh = (ushort*)(y2g + 48 * TT);  Wql = Wqh + (size_t)2304 * CC;
        Wph = Wql + (size_t)2304 * CC;   Wpl = Wph + (size_t)CC * CC;
        yh = (ushort*)w;  yl = yh + PL;
    } else {
        Wqh = (ushort*)w;  Wql = Wqh + (size_t)2304 * CC;
        yh = (ushort*)w;   yl = yh + PL;
        qh = (ushort*)(w + 2 * PL * 2);
        ql = qh + PL;  kh = ql + PL;  kl = kh + PL;  vT = kl + PL;
        Wph = vT + PL;  Wpl = Wph + (size_t)CC * CC;
        x2g = (float*)(Wpl + (size_t)CC * CC);  y2g = x2g + 48 * TT;
        xh = xl = nullptr;
    }

    wprep<<<2304 * CC / 4 / 256, 256, 0, stream>>>(Wqkv, Wqh, Wql, 2304 * CC / 4);
    wprep<<<CC * CC / 4 / 256, 256, 0, stream>>>(Wproj, Wph, Wpl, CC * CC / 4);
    if (ps) {
        wprep<<<4096 * CC / 4 / 256, 256, 0, stream>>>(x, xh, xl, 4096 * CC / 4);
        gemm_qkv<true><<<dim3(18, 32), 256, 0, stream>>>(x, xh, xl, Wqh, Wql, kcurv,
                                                         qh, ql, kh, kl, vT, x2g, y2g);
    } else {
        gemm_qkv<false><<<dim3(18, 32), 256, 0, stream>>>(x, nullptr, nullptr, Wqh, Wql,
                                                          kcurv, qh, ql, kh, kl, vT, x2g, y2g);
    }
    hyp_attn<<<1536, 512, 0, stream>>>(qh, ql, kh, kl, vT, x2g, y2g, kcurv, yh, yl);
    gemm_out<<<dim3(6, 32), 256, 0, stream>>>(yh, yl, Wph, Wpl, out);
}

// Round 10
// 178.219 us; speedup vs baseline: 1.5196x; 1.2210x over previous
//
#include <hip/hip_runtime.h>
#include <hip/hip_bf16.h>
#include <math.h>

#define PROJ_EPSF 0.004f
#define MIN_NORMF 1e-15f
#define ATANH_EPSF 1e-5f
#define WEI_EPSF 1e-3f
#define LN2F 0.69314718055994531f

#define TT 1024
#define CC 768
#define HH 12
#define BBATCH 4

typedef unsigned long long ull;
typedef __attribute__((ext_vector_type(4))) float f32x4;
typedef __attribute__((ext_vector_type(8))) short bf16x8;

#define MFMA(a, b, c) __builtin_amdgcn_mfma_f32_16x16x32_bf16(a, b, c, 0, 0, 0)

static __device__ __forceinline__ uint cvtpk(float a, float b) {
    uint r;
    asm("v_cvt_pk_bf16_f32 %0, %1, %2" : "=v"(r) : "v"(a), "v"(b));
    return r;
}
static __device__ __forceinline__ ushort f2bf(float f) {
    uint u = __float_as_uint(f);
    u += 0x7fffu + ((u >> 16) & 1u);
    return (ushort)(u >> 16);
}
static __device__ __forceinline__ float bf2f(ushort h) {
    return __uint_as_float(((uint)h) << 16);
}
static __device__ __forceinline__ void split4(const float4& f, ull& hp, ull& lp) {
    uint h01 = cvtpk(f.x, f.y), h23 = cvtpk(f.z, f.w);
    float r0 = f.x - __uint_as_float(h01 << 16);
    float r1 = f.y - __uint_as_float(h01 & 0xffff0000u);
    float r2 = f.z - __uint_as_float(h23 << 16);
    float r3 = f.w - __uint_as_float(h23 & 0xffff0000u);
    uint l01 = cvtpk(r0, r1), l23 = cvtpk(r2, r3);
    hp = ((ull)h23 << 32) | h01;
    lp = ((ull)l23 << 32) | l01;
}
// async global -> LDS, 16 B per lane (per-lane global addr, wave-uniform LDS base)
static __device__ __forceinline__ void gl_lds16(const void* g, void* l) {
    __builtin_amdgcn_global_load_lds(
        (const __attribute__((address_space(1))) unsigned int*)g,
        (__attribute__((address_space(3))) unsigned int*)l, 16, 0, 0);
}

// ---------------- prep: f32 -> bf16 hi/lo planes ----------------
__global__ __launch_bounds__(256) void wprep(const float* __restrict__ W,
                                             ushort* __restrict__ Wh,
                                             ushort* __restrict__ Wl, int n4) {
    int i = blockIdx.x * 256 + threadIdx.x;
    if (i < n4) {
        float4 f = ((const float4*)W)[i];
        ull hp, lp;
        split4(f, hp, lp);
        ((ull*)Wh)[i] = hp;
        ((ull*)Wl)[i] = lp;
    }
}

// ---------------- fused QKV GEMM + Poincare projection + layout ----------------
template <bool PS>
__global__ __launch_bounds__(256) void gemm_qkv(
        const float* __restrict__ xf, const ushort* __restrict__ xhp,
        const ushort* __restrict__ xlp, const ushort* __restrict__ Wh,
        const ushort* __restrict__ Wl, const float* __restrict__ kcurv,
        ushort* __restrict__ qh, ushort* __restrict__ ql,
        ushort* __restrict__ kh, ushort* __restrict__ kl,
        ushort* __restrict__ vT, float* __restrict__ x2g,
        float* __restrict__ y2g) {
    __shared__ ushort Ah[128 * 40], Al[128 * 40], Bh[128 * 40], Bl[128 * 40];
    const int tid = threadIdx.x, lane = tid & 63, wv = tid >> 6;
    const int wr = wv >> 1, wc = wv & 1, lr = lane & 15, lg = lane >> 4;
    const int m0 = blockIdx.y * 128, n0 = blockIdx.x * 128;
    const bool isV = (n0 >= 2 * CC);
    const int srow = tid >> 1, sk0 = (tid & 1) * 16;
    const float* Ap = xf + (size_t)(m0 + srow) * CC + sk0;
    const ushort* Axh = xhp + (size_t)(m0 + srow) * CC + sk0;
    const ushort* Axl = xlp + (size_t)(m0 + srow) * CC + sk0;
    const ushort* Bhp = Wh + (size_t)(n0 + srow) * CC + sk0;
    const ushort* Blp = Wl + (size_t)(n0 + srow) * CC + sk0;

    f32x4 acc[4][4] = {};
    float4 av[4];
    bf16x8 ahv[2], alv[2], bhv[2], blv[2];
    if constexpr (PS) {
        ahv[0] = *(const bf16x8*)(Axh);
        ahv[1] = *(const bf16x8*)(Axh + 8);
        if (!isV) {
            alv[0] = *(const bf16x8*)(Axl);
            alv[1] = *(const bf16x8*)(Axl + 8);
        }
    } else {
#pragma unroll
        for (int q = 0; q < 4; ++q) av[q] = *(const float4*)(Ap + 4 * q);
    }
    bhv[0] = *(const bf16x8*)(Bhp);
    bhv[1] = *(const bf16x8*)(Bhp + 8);
    if (!isV) {
        blv[0] = *(const bf16x8*)(Blp);
        blv[1] = *(const bf16x8*)(Blp + 8);
    }

    for (int kk = 0; kk < CC; kk += 32) {
        __syncthreads();
        if constexpr (PS) {
            *(bf16x8*)&Ah[srow * 40 + sk0] = ahv[0];
            *(bf16x8*)&Ah[srow * 40 + sk0 + 8] = ahv[1];
            if (!isV) {
                *(bf16x8*)&Al[srow * 40 + sk0] = alv[0];
                *(bf16x8*)&Al[srow * 40 + sk0 + 8] = alv[1];
            }
        } else {
#pragma unroll
            for (int q = 0; q < 4; ++q) {
                ull hp, lp;
                split4(av[q], hp, lp);
                *(ull*)&Ah[srow * 40 + sk0 + 4 * q] = hp;
                if (!isV) *(ull*)&Al[srow * 40 + sk0 + 4 * q] = lp;
            }
        }
        *(bf16x8*)&Bh[srow * 40 + sk0] = bhv[0];
        *(bf16x8*)&Bh[srow * 40 + sk0 + 8] = bhv[1];
        if (!isV) {
            *(bf16x8*)&Bl[srow * 40 + sk0] = blv[0];
            *(bf16x8*)&Bl[srow * 40 + sk0 + 8] = blv[1];
        }
        __syncthreads();
        if (kk + 32 < CC) {
            if constexpr (PS) {
                ahv[0] = *(const bf16x8*)(Axh + kk + 32);
                ahv[1] = *(const bf16x8*)(Axh + kk + 40);
                if (!isV) {
                    alv[0] = *(const bf16x8*)(Axl + kk + 32);
                    alv[1] = *(const bf16x8*)(Axl + kk + 40);
                }
            } else {
#pragma unroll
                for (int q = 0; q < 4; ++q)
                    av[q] = *(const float4*)(Ap + kk + 32 + 4 * q);
            }
            bhv[0] = *(const bf16x8*)(Bhp + kk + 32);
            bhv[1] = *(const bf16x8*)(Bhp + kk + 40);
            if (!isV) {
                blv[0] = *(const bf16x8*)(Blp + kk + 32);
                blv[1] = *(const bf16x8*)(Blp + kk + 40);
            }
        }
        if (!isV) {
            bf16x8 a_h[4], a_l[4];
#pragma unroll
            for (int m = 0; m < 4; ++m) {
                const int off = (wr * 64 + m * 16 + lr) * 40 + lg * 8;
                a_h[m] = *(const bf16x8*)&Ah[off];
                a_l[m] = *(const bf16x8*)&Al[off];
            }
#pragma unroll
            for (int n = 0; n < 4; ++n) {
                const int off = (wc * 64 + n * 16 + lr) * 40 + lg * 8;
                bf16x8 b_h = *(const bf16x8*)&Bh[off];
                bf16x8 b_l = *(const bf16x8*)&Bl[off];
#pragma unroll
                for (int m = 0; m < 4; ++m) {
                    acc[m][n] = MFMA(a_h[m], b_h, acc[m][n]);
                    acc[m][n] = MFMA(a_h[m], b_l, acc[m][n]);
                    acc[m][n] = MFMA(a_l[m], b_h, acc[m][n]);
                }
            }
        } else {
            bf16x8 a_h[4], b_h[4];
#pragma unroll
            for (int m = 0; m < 4; ++m)
                a_h[m] = *(const bf16x8*)&Ah[(wr * 64 + m * 16 + lr) * 40 + lg * 8];
#pragma unroll
            for (int n = 0; n < 4; ++n)
                b_h[n] = *(const bf16x8*)&Bh[(wc * 64 + n * 16 + lr) * 40 + lg * 8];
#pragma unroll
            for (int n = 0; n < 4; ++n)
#pragma unroll
                for (int m = 0; m < 4; ++m)
                    acc[n][m] = MFMA(b_h[n], a_h[m], acc[n][m]);
        }
    }
    // ---- epilogue ----
    if (isV) {
        const int hd = (n0 - 2 * CC) / 64 + wc;
#pragma unroll
        for (int n = 0; n < 4; ++n)
#pragma unroll
            for (int m = 0; m < 4; ++m)
#pragma unroll
                for (int r = 0; r < 4; ++r) {
                    const int dl = n * 16 + lg * 4 + r;
                    const int tok = m0 + wr * 64 + m * 16 + lr;
                    vT[(size_t)(hd * 64 + dl) * 4096 + tok] = f2bf(acc[n][m][r]);
                }
    } else {
        const bool isQ = (n0 < CC);
        const int hd = (isQ ? n0 : n0 - CC) / 64 + wc;
        ushort* ph = isQ ? qh : kh;
        ushort* pl = isQ ? ql : kl;
        float* sg = isQ ? x2g : y2g;
        const float kcv = kcurv[hd];
        const float mxn = (1.0f - PROJ_EPSF) / sqrtf(kcv);
        const float mxn2 = mxn * mxn;
#pragma unroll
        for (int m = 0; m < 4; ++m)
#pragma unroll
            for (int r = 0; r < 4; ++r) {
                float s = 0.f;
#pragma unroll
                for (int n = 0; n < 4; ++n) s = fmaf(acc[m][n][r], acc[m][n][r], s);
                s += __shfl_xor(s, 1);
                s += __shfl_xor(s, 2);
                s += __shfl_xor(s, 4);
                s += __shfl_xor(s, 8);
                float scale = 1.0f, x2v = s;
                if (s > mxn2) {
                    scale = mxn * __builtin_amdgcn_rcpf(sqrtf(s));
                    x2v = s * scale * scale;
                }
                const int tok = m0 + wr * 64 + m * 16 + lg * 4 + r;
                const size_t rowb = (size_t)tok * CC + (isQ ? n0 : n0 - CC) + wc * 64;
#pragma unroll
                for (int n = 0; n < 4; ++n) {
                    const float v = acc[m][n][r] * scale;
                    const ushort hb = f2bf(v);
                    ph[rowb + n * 16 + lr] = hb;
                    pl[rowb + n * 16 + lr] = f2bf(v - bf2f(hb));
                }
                if (lr == 0)
                    sg[(size_t)((tok >> 10) * HH + hd) * TT + (tok & 1023)] = x2v;
            }
    }
}

// ---------------- LDS-staged 2-phase fused hyperbolic attention ----------------
// Block = 32 q-rows (2 waves, wave w owns rows (g32*2+w)*16..+15), uniform
// TC = g32/2+1 tiles.  Both waves march the SAME key tile: K(hi+lo) double-
// buffered + V single-buffered in LDS via global_load_lds (async, 0 VGPR),
// source pre-swizzled so ds_read_b128 is bank-conflict-free.  2 barriers/tile.
__global__ __launch_bounds__(128) void hyp_attn(
        const ushort* __restrict__ qh, const ushort* __restrict__ ql,
        const ushort* __restrict__ kh, const ushort* __restrict__ kl,
        const ushort* __restrict__ vT, const float* __restrict__ x2g,
        const float* __restrict__ y2g, const float* __restrict__ kcurv,
        ushort* __restrict__ yh, ushort* __restrict__ yl) {
    const int ib = (int)blockIdx.x;          // 0..1535
    const int xcd = ib & 7, t = ib >> 3;     // t 0..191 per XCD
    const int tcr = t / 12;                  // 0..15, tile-count rank (big first)
    const int which = t - tcr * 12;
    const int g32 = (15 - tcr) * 2 + (which & 1);   // 32-row group 0..31
    const int bh = (which >> 1) * 8 + xcd;   // bh%8 == XCD id
    const int b = bh / HH, h = bh - b * HH;
    const int tid = threadIdx.x, lane = tid & 63, wv = tid >> 6;   // wv 0..1
    const int lr = lane & 15, lg = lane >> 4;
    const int rg = g32 * 2 + wv;             // 16-row group
    const int rgq = g32 >> 1;                // last key-tile index (uniform)

    __shared__ char ldsK[2][16384];          // [buf][hi 8KB | lo 8KB]
    __shared__ char ldsV[8192];              // [dim][key] swizzled
    __shared__ ushort wtb[2][16 * 72];
    ushort* wtw = wtb[wv];

    const float kc = kcurv[h];
    const float sk = sqrtf(kc);
    const float distc = LN2F / sk;
    const float d2c = distc * distc;
    const float twokc = 2.0f * kc;
    const float cA = 1.0f - ATANH_EPSF;

    const size_t qrb = (size_t)(b * TT + rg * 16 + lr) * CC + h * 64 + lg * 8;
    const bf16x8 qH0 = *(const bf16x8*)(qh + qrb), qH1 = *(const bf16x8*)(qh + qrb + 32);
    const bf16x8 qL0 = *(const bf16x8*)(ql + qrb), qL1 = *(const bf16x8*)(ql + qrb + 32);
    const float4 x2v = *(const float4*)&x2g[(size_t)bh * TT + rg * 16 + lg * 4];
    const float x2a[4] = { x2v.x, x2v.y, x2v.z, x2v.w };
    float kx2[4], Bc[4], Bc2[4];
#pragma unroll
    for (int r = 0; r < 4; ++r) {
        kx2[r] = kc * x2a[r];
        Bc[r] = 1.0f - kx2[r];
        Bc2[r] = Bc[r] * Bc[r];
    }

    // staging lane constants (source pre-swizzle; rule #21 both-sides)
    const int srow8 = lane >> 3;                 // row within 8-row call group
    const int sgrp = (lane & 7) ^ (srow8 & 7);   // swizzled dim/key group
    // ds_read swizzled slot offsets (bytes) for k-slices 0/1
    const int so0 = ((lg ^ (lr & 7)) << 4);
    const int so1 = (((4 + lg) ^ (lr & 7)) << 4);
    const int lro = lr << 7;                     // row byte offset (128 B rows)

#define STAGE_K(BUF, J0)                                                          \
    { _Pragma("unroll") for (int c4 = 0; c4 < 4; ++c4) {                          \
        const int c = wv * 4 + c4;                                                \
        const size_t gsrc = (size_t)(b * TT + (J0) + c * 8 + srow8) * CC + h * 64 + sgrp * 8; \
        gl_lds16(kh + gsrc, (char*)(BUF) + c * 1024);                             \
        gl_lds16(kl + gsrc, (char*)(BUF) + 8192 + c * 1024);                      \
    } }
#define STAGE_V(J0)                                                               \
    { _Pragma("unroll") for (int c4 = 0; c4 < 4; ++c4) {                          \
        const int c = wv * 4 + c4;                                                \
        gl_lds16(vT + (size_t)(h * 64 + c * 8 + srow8) * 4096 + b * TT + (J0) + sgrp * 8, \
                 ldsV + c * 1024);                                                \
    } }

#define TRANSF(NN, SA, Y2R)                                                        \
    {                                                                              \
        const float ky2 = kc * (Y2R);                                              \
        const float p1 = 1.0f + ky2;                                               \
        const int jg = j0 + NN * 16 + lr;                                          \
        _Pragma("unroll") for (int r = 0; r < 4; ++r) {                            \
            const float xy = SA[r];                                                \
            const float t2 = twokc * xy;                                           \
            const float Aa = p1 - t2;                                              \
            const float dn = fmaxf(fmaf(kx2[r], ky2, 1.0f) - t2, MIN_NORMF);       \
            const float ABxy = Aa * (Bc[r] * xy);                                  \
            const float c1 = fmaf(Bc2[r], (Y2R), -2.0f * ABxy);                    \
            const float num2 = fmaf(Aa * Aa, x2a[r], c1);                          \
            const float s = sqrtf(fmaxf(num2, MIN_NORMF));                         \
            const float sm = fminf(sk * s, cA * dn);                               \
            const float L = __builtin_amdgcn_logf((dn + sm) *                      \
                                __builtin_amdgcn_rcpf(dn - sm));                   \
            float w = __builtin_amdgcn_rcpf(fmaf(L * L, d2c, WEI_EPSF));           \
            if (mk && (jg > rg * 16 + lg * 4 + r)) w = 0.0f;                       \
            wtw[(lg * 4 + r) * 72 + NN * 16 + lr] = f2bf(w);                       \
            wsum[r] += w;                                                          \
        }                                                                          \
    }

    f32x4 pv[4] = {};
    float wsum[4] = {};

    // prologue: stage K(0) into buf 0
    STAGE_K(ldsK[0], 0)
    asm volatile("s_waitcnt vmcnt(0)" ::: "memory");
    __syncthreads();

    int cur = 0;
    for (int jt = 0; jt <= rgq; ++jt) {
        const int j0 = jt * 64;
        const bool mk = (jt == rgq);
        // ---- async stage: next K tile + this V tile ----
        if (jt < rgq) STAGE_K(ldsK[cur ^ 1], j0 + 64)
        STAGE_V(j0)
        const size_t y2b = (size_t)bh * TT + j0 + lr;
        const float y2n[4] = { y2g[y2b], y2g[y2b + 16], y2g[y2b + 32], y2g[y2b + 48] };
        // ---- S = qp.kp^T from LDS (hi/lo, conflict-free swizzled reads) ----
        __builtin_amdgcn_s_setprio(1);
        f32x4 sacc[4] = {};
#pragma unroll
        for (int n = 0; n < 4; ++n) {
            const char* p = ldsK[cur] + n * 2048 + lro;
            bf16x8 h0 = *(const bf16x8*)(p + so0);
            bf16x8 h1 = *(const bf16x8*)(p + so1);
            bf16x8 l0 = *(const bf16x8*)(p + 8192 + so0);
            bf16x8 l1 = *(const bf16x8*)(p + 8192 + so1);
            sacc[n] = MFMA(qH0, h0, sacc[n]);
            sacc[n] = MFMA(qH0, l0, sacc[n]);
            sacc[n] = MFMA(qL0, h0, sacc[n]);
            sacc[n] = MFMA(qH1, h1, sacc[n]);
            sacc[n] = MFMA(qH1, l1, sacc[n]);
            sacc[n] = MFMA(qL1, h1, sacc[n]);
        }
        // ---- transform -> wt ----
        TRANSF(0, sacc[0], y2n[0])
        TRANSF(1, sacc[1], y2n[1])
        TRANSF(2, sacc[2], y2n[2])
        TRANSF(3, sacc[3], y2n[3])
        __builtin_amdgcn_s_setprio(0);
        asm volatile("s_waitcnt vmcnt(0)" ::: "memory");
        __syncthreads();   // stages landed everywhere; K(cur) reads done
        // ---- PV from LDS ----
        __builtin_amdgcn_s_setprio(1);
        bf16x8 pw0 = *(const bf16x8*)&wtw[lr * 72 + lg * 8];
        bf16x8 pw1 = *(const bf16x8*)&wtw[lr * 72 + 32 + lg * 8];
#pragma unroll
        for (int n = 0; n < 4; ++n) {
            const char* p = ldsV + n * 2048 + lro;
            bf16x8 v0 = *(const bf16x8*)(p + so0);
            bf16x8 v1 = *(const bf16x8*)(p + so1);
            pv[n] = MFMA(pw0, v0, pv[n]);
            pv[n] = MFMA(pw1, v1, pv[n]);
        }
        __builtin_amdgcn_s_setprio(0);
        __syncthreads();   // PV done: ldsV / wt / ldsK[cur] reusable
        cur ^= 1;
    }

    // ---- epilogue: den reduce + y hi/lo write (wave-local rows) ----
    float den[4];
#pragma unroll
    for (int r = 0; r < 4; ++r) {
        float s = wsum[r];
        s += __shfl_xor(s, 1);
        s += __shfl_xor(s, 2);
        s += __shfl_xor(s, 4);
        s += __shfl_xor(s, 8);
        den[r] = s;
    }
#pragma unroll
    for (int r = 0; r < 4; ++r) {
        const float iv = __builtin_amdgcn_rcpf(den[r]);
        const size_t rowb = (size_t)(b * TT + rg * 16 + lg * 4 + r) * CC + h * 64;
#pragma unroll
        for (int n = 0; n < 4; ++n) {
            const float val = pv[n][r] * iv;
            const ushort hb = f2bf(val);
            yh[rowb + n * 16 + lr] = hb;
            yl[rowb + n * 16 + lr] = f2bf(val - bf2f(hb));
        }
    }
#undef TRANSF
#undef STAGE_K
#undef STAGE_V
}

// ---------------- output GEMM: out = y @ Wproj^T (pre-split A and B) ----------------
__global__ __launch_bounds__(256) void gemm_out(const ushort* __restrict__ Ahp,
                                                const ushort* __restrict__ Alp,
                                                const ushort* __restrict__ Wh,
                                                const ushort* __restrict__ Wl,
                                                float* __restrict__ C) {
    __shared__ ushort Ah[128 * 40], Al[128 * 40], Bh[128 * 40], Bl[128 * 40];
    const int tid = threadIdx.x, lane = tid & 63, wv = tid >> 6;
    const int wr = wv >> 1, wc = wv & 1, lr = lane & 15, lg = lane >> 4;
    const int m0 = blockIdx.y * 128, n0 = blockIdx.x * 128;
    const int srow = tid >> 1, sk0 = (tid & 1) * 16;
    const ushort* Ahq = Ahp + (size_t)(m0 + srow) * CC + sk0;
    const ushort* Alq = Alp + (size_t)(m0 + srow) * CC + sk0;
    const ushort* Bhp = Wh + (size_t)(n0 + srow) * CC + sk0;
    const ushort* Blp = Wl + (size_t)(n0 + srow) * CC + sk0;

    f32x4 acc[4][4] = {};
    bf16x8 ahv[2], alv[2], bhv[2], blv[2];
    ahv[0] = *(const bf16x8*)(Ahq);      ahv[1] = *(const bf16x8*)(Ahq + 8);
    alv[0] = *(const bf16x8*)(Alq);      alv[1] = *(const bf16x8*)(Alq + 8);
    bhv[0] = *(const bf16x8*)(Bhp);      bhv[1] = *(const bf16x8*)(Bhp + 8);
    blv[0] = *(const bf16x8*)(Blp);      blv[1] = *(const bf16x8*)(Blp + 8);

    for (int kk = 0; kk < CC; kk += 32) {
        __syncthreads();
        *(bf16x8*)&Ah[srow * 40 + sk0] = ahv[0];
        *(bf16x8*)&Ah[srow * 40 + sk0 + 8] = ahv[1];
        *(bf16x8*)&Al[srow * 40 + sk0] = alv[0];
        *(bf16x8*)&Al[srow * 40 + sk0 + 8] = alv[1];
        *(bf16x8*)&Bh[srow * 40 + sk0] = bhv[0];
        *(bf16x8*)&Bh[srow * 40 + sk0 + 8] = bhv[1];
        *(bf16x8*)&Bl[srow * 40 + sk0] = blv[0];
        *(bf16x8*)&Bl[srow * 40 + sk0 + 8] = blv[1];
        __syncthreads();
        if (kk + 32 < CC) {
            ahv[0] = *(const bf16x8*)(Ahq + kk + 32);
            ahv[1] = *(const bf16x8*)(Ahq + kk + 40);
            alv[0] = *(const bf16x8*)(Alq + kk + 32);
            alv[1] = *(const bf16x8*)(Alq + kk + 40);
            bhv[0] = *(const bf16x8*)(Bhp + kk + 32);
            bhv[1] = *(const bf16x8*)(Bhp + kk + 40);
            blv[0] = *(const bf16x8*)(Blp + kk + 32);
            blv[1] = *(const bf16x8*)(Blp + kk + 40);
        }
        bf16x8 a_h[4], a_l[4];
#pragma unroll
        for (int m = 0; m < 4; ++m) {
            const int off = (wr * 64 + m * 16 + lr) * 40 + lg * 8;
            a_h[m] = *(const bf16x8*)&Ah[off];
            a_l[m] = *(const bf16x8*)&Al[off];
        }
#pragma unroll
        for (int n = 0; n < 4; ++n) {
            const int off = (wc * 64 + n * 16 + lr) * 40 + lg * 8;
            bf16x8 b_h = *(const bf16x8*)&Bh[off];
            bf16x8 b_l = *(const bf16x8*)&Bl[off];
#pragma unroll
            for (int m = 0; m < 4; ++m) {
                acc[m][n] = MFMA(a_h[m], b_h, acc[m][n]);
                acc[m][n] = MFMA(a_h[m], b_l, acc[m][n]);
                acc[m][n] = MFMA(a_l[m], b_h, acc[m][n]);
            }
        }
    }
#pragma unroll
    for (int m = 0; m < 4; ++m)
#pragma unroll
        for (int n = 0; n < 4; ++n)
#pragma unroll
            for (int r = 0; r < 4; ++r)
                C[(size_t)(m0 + wr * 64 + m * 16 + lg * 4 + r) * CC + n0 + wc * 64 + n * 16 + lr] =
                    acc[m][n][r];
}

extern "C" void kernel_launch(void* const* d_in, const int* in_sizes, int n_in,
                              void* d_out, int out_size, void* d_ws, size_t ws_size,
                              hipStream_t stream) {
    const float* x     = (const float*)d_in[0];
    const float* Wqkv  = (const float*)d_in[1];
    const float* Wproj = (const float*)d_in[2];
    const float* kcurv = (const float*)d_in[3];
    float* out = (float*)d_out;

    const size_t PL = (size_t)4096 * CC;
    char* w = (char*)d_ws;
    const bool ps = ws_size >= 53870592ULL;

    ushort *xh, *xl, *qh, *ql, *kh, *kl, *vT, *Wqh, *Wql, *Wph, *Wpl, *yh, *yl;
    float *x2g, *y2g;
    if (ps) {
        xh = (ushort*)w;          xl = xh + PL;     // reused as yh/yl later
        qh = xl + PL;  ql = qh + PL;  kh = ql + PL;  kl = kh + PL;  vT = kl + PL;
        x2g = (float*)(vT + PL);  y2g = x2g + 48 * TT;
        Wqh = (ushort*)(y2g + 48 * TT);  Wql = Wqh + (size_t)2304 * CC;
        Wph = Wql + (size_t)2304 * CC;   Wpl = Wph + (size_t)CC * CC;
        yh = (ushort*)w;  yl = yh + PL;
    } else {
        Wqh = (ushort*)w;  Wql = Wqh + (size_t)2304 * CC;
        yh = (ushort*)w;   yl = yh + PL;
        qh = (ushort*)(w + 2 * PL * 2);
        ql = qh + PL;  kh = ql + PL;  kl = kh + PL;  vT = kl + PL;
        Wph = vT + PL;  Wpl = Wph + (size_t)CC * CC;
        x2g = (float*)(Wpl + (size_t)CC * CC);  y2g = x2g + 48 * TT;
        xh = xl = nullptr;
    }

    wprep<<<2304 * CC / 4 / 256, 256, 0, stream>>>(Wqkv, Wqh, Wql, 2304 * CC / 4);
    wprep<<<CC * CC / 4 / 256, 256, 0, stream>>>(Wproj, Wph, Wpl, CC * CC / 4);
    if (ps) {
        wprep<<<4096 * CC / 4 / 256, 256, 0, stream>>>(x, xh, xl, 4096 * CC / 4);
        gemm_qkv<true><<<dim3(18, 32), 256, 0, stream>>>(x, xh, xl, Wqh, Wql, kcurv,
                                                         qh, ql, kh, kl, vT, x2g, y2g);
    } else {
        gemm_qkv<false><<<dim3(18, 32), 256, 0, stream>>>(x, nullptr, nullptr, Wqh, Wql,
                                                          kcurv, qh, ql, kh, kl, vT, x2g, y2g);
    }
    hyp_attn<<<1536, 128, 0, stream>>>(qh, ql, kh, kl, vT, x2g, y2g, kcurv, yh, yl);
    gemm_out<<<dim3(6, 32), 256, 0, stream>>>(yh, yl, Wph, Wpl, out);
}

// Round 11
// 156.109 us; speedup vs baseline: 1.7348x; 1.1416x over previous
//
#include <hip/hip_runtime.h>
#include <hip/hip_bf16.h>
#include <math.h>

#define PROJ_EPSF 0.004f
#define MIN_NORMF 1e-15f
#define ATANH_EPSF 1e-5f
#define WEI_EPSF 1e-3f
#define LN2F 0.69314718055994531f

#define TT 1024
#define CC 768
#define HH 12
#define BBATCH 4

typedef unsigned long long ull;
typedef __attribute__((ext_vector_type(4))) float f32x4;
typedef __attribute__((ext_vector_type(8))) short bf16x8;

#define MFMA(a, b, c) __builtin_amdgcn_mfma_f32_16x16x32_bf16(a, b, c, 0, 0, 0)

static __device__ __forceinline__ uint cvtpk(float a, float b) {
    uint r;
    asm("v_cvt_pk_bf16_f32 %0, %1, %2" : "=v"(r) : "v"(a), "v"(b));
    return r;
}
static __device__ __forceinline__ ushort f2bf(float f) {
    uint u = __float_as_uint(f);
    u += 0x7fffu + ((u >> 16) & 1u);
    return (ushort)(u >> 16);
}
static __device__ __forceinline__ float bf2f(ushort h) {
    return __uint_as_float(((uint)h) << 16);
}
static __device__ __forceinline__ void split4(const float4& f, ull& hp, ull& lp) {
    uint h01 = cvtpk(f.x, f.y), h23 = cvtpk(f.z, f.w);
    float r0 = f.x - __uint_as_float(h01 << 16);
    float r1 = f.y - __uint_as_float(h01 & 0xffff0000u);
    float r2 = f.z - __uint_as_float(h23 << 16);
    float r3 = f.w - __uint_as_float(h23 & 0xffff0000u);
    uint l01 = cvtpk(r0, r1), l23 = cvtpk(r2, r3);
    hp = ((ull)h23 << 32) | h01;
    lp = ((ull)l23 << 32) | l01;
}
union pk16 { bf16x8 v; ull u[2]; };
// async global -> LDS, 16 B per lane (per-lane global addr, wave-uniform LDS base)
static __device__ __forceinline__ void gl_lds16(const void* g, void* l) {
    __builtin_amdgcn_global_load_lds(
        (const __attribute__((address_space(1))) unsigned int*)g,
        (__attribute__((address_space(3))) unsigned int*)l, 16, 0, 0);
}

// ---------------- prep: f32 -> bf16 hi/lo planes ----------------
__global__ __launch_bounds__(256) void wprep(const float* __restrict__ W,
                                             ushort* __restrict__ Wh,
                                             ushort* __restrict__ Wl, int n4) {
    int i = blockIdx.x * 256 + threadIdx.x;
    if (i < n4) {
        float4 f = ((const float4*)W)[i];
        ull hp, lp;
        split4(f, hp, lp);
        ((ull*)Wh)[i] = hp;
        ((ull*)Wl)[i] = lp;
    }
}

// ---------------- fused QKV GEMM + projection + layout (gl_lds B) ----------------
// 128x128 tile, grid (32 m, 18 n) m-fastest: per-XCD A footprint = 4 m-tiles
// (L2-resident).  B hi/lo staged via global_load_lds (async, swizzled source,
// rule-21 paired XOR read).  A: f32 -> hi/lo split in reg, swizzled ds_write.
// LDS planes: 64 packed rows x 128 B (pairs of 64B k-rows), 8 KB each.
__global__ __launch_bounds__(256) void gemm_qkv(
        const float* __restrict__ x, const ushort* __restrict__ Wh,
        const ushort* __restrict__ Wl, const float* __restrict__ kcurv,
        ushort* __restrict__ qh, ushort* __restrict__ ql,
        ushort* __restrict__ kh, ushort* __restrict__ kl,
        ushort* __restrict__ vT, float* __restrict__ x2g,
        float* __restrict__ y2g) {
    __shared__ ushort Ah[64 * 64], Al[64 * 64], Bh[64 * 64], Bl[64 * 64];
    const int tid = threadIdx.x, lane = tid & 63, wv = tid >> 6;
    const int wr = wv >> 1, wc = wv & 1, lr = lane & 15, lg = lane >> 4;
    const int m0 = blockIdx.x * 128, n0 = blockIdx.y * 128;
    const bool isV = (n0 >= 2 * CC);

    // A staging: thread covers (row = tid>>1, k-half = tid&1) -> 16 f32
    const int arow = tid >> 1, akh = tid & 1;
    const float* Ap = x + (size_t)(m0 + arow) * CC + akh * 16;
    const int ap_ = arow >> 1;
    const int ag0 = 4 * (arow & 1) + 2 * akh;
    const int aoff0 = ap_ * 128 + ((ag0 ^ (ap_ & 7)) << 4);
    const int aoff1 = ap_ * 128 + (((ag0 + 1) ^ (ap_ & 7)) << 4);
    // B staging: wave wv issues calls {2wv, 2wv+1} per plane
    const int c0 = 2 * wv, c1 = 2 * wv + 1;
    const int p0 = 8 * c0 + (lane >> 3), q0 = (lane & 7) ^ (p0 & 7);
    const int p1 = 8 * c1 + (lane >> 3), q1 = (lane & 7) ^ (p1 & 7);
    const size_t bs0 = (size_t)(n0 + 2 * p0 + (q0 >> 2)) * CC + (q0 & 3) * 8;
    const size_t bs1 = (size_t)(n0 + 2 * p1 + (q1 >> 2)) * CC + (q1 & 3) * 8;
    // fragment-read constants
    const int goff = (((4 * (lr & 1) + lg) ^ ((lr >> 1) & 7)) << 4);
    const int pa = wr * 32 + (lr >> 1);
    const int pb = wc * 32 + (lr >> 1);

    f32x4 acc[4][4] = {};
    float4 av[4];
#pragma unroll
    for (int q = 0; q < 4; ++q) av[q] = *(const float4*)(Ap + 4 * q);

    for (int kk = 0; kk < CC; kk += 32) {
        __syncthreads();
        // ---- A: split + swizzled ds_write (2 b128 per plane) ----
        pk16 h, l;
        split4(av[0], h.u[0], l.u[0]);
        split4(av[1], h.u[1], l.u[1]);
        *(bf16x8*)((char*)Ah + aoff0) = h.v;
        if (!isV) *(bf16x8*)((char*)Al + aoff0) = l.v;
        split4(av[2], h.u[0], l.u[0]);
        split4(av[3], h.u[1], l.u[1]);
        *(bf16x8*)((char*)Ah + aoff1) = h.v;
        if (!isV) *(bf16x8*)((char*)Al + aoff1) = l.v;
        // ---- B: async global -> LDS ----
        gl_lds16(Wh + bs0 + kk, (char*)Bh + c0 * 1024);
        gl_lds16(Wh + bs1 + kk, (char*)Bh + c1 * 1024);
        if (!isV) {
            gl_lds16(Wl + bs0 + kk, (char*)Bl + c0 * 1024);
            gl_lds16(Wl + bs1 + kk, (char*)Bl + c1 * 1024);
        }
        asm volatile("s_waitcnt vmcnt(0)" ::: "memory");
        __syncthreads();
        // ---- prefetch next A (latency hidden under MFMA) ----
        if (kk + 32 < CC)
#pragma unroll
            for (int q = 0; q < 4; ++q)
                av[q] = *(const float4*)(Ap + kk + 32 + 4 * q);
        // ---- MFMA from LDS ----
        if (!isV) {
            bf16x8 a_h[4], a_l[4];
#pragma unroll
            for (int m = 0; m < 4; ++m) {
                const int off = (pa + m * 8) * 128 + goff;
                a_h[m] = *(const bf16x8*)((char*)Ah + off);
                a_l[m] = *(const bf16x8*)((char*)Al + off);
            }
#pragma unroll
            for (int n = 0; n < 4; ++n) {
                const int off = (pb + n * 8) * 128 + goff;
                bf16x8 b_h = *(const bf16x8*)((char*)Bh + off);
                bf16x8 b_l = *(const bf16x8*)((char*)Bl + off);
#pragma unroll
                for (int m = 0; m < 4; ++m) {
                    acc[m][n] = MFMA(a_h[m], b_h, acc[m][n]);
                    acc[m][n] = MFMA(a_h[m], b_l, acc[m][n]);
                    acc[m][n] = MFMA(a_l[m], b_h, acc[m][n]);
                }
            }
        } else {
            bf16x8 a_h[4], b_h[4];
#pragma unroll
            for (int m = 0; m < 4; ++m)
                a_h[m] = *(const bf16x8*)((char*)Ah + (pa + m * 8) * 128 + goff);
#pragma unroll
            for (int n = 0; n < 4; ++n)
                b_h[n] = *(const bf16x8*)((char*)Bh + (pb + n * 8) * 128 + goff);
#pragma unroll
            for (int n = 0; n < 4; ++n)
#pragma unroll
                for (int m = 0; m < 4; ++m)
                    acc[n][m] = MFMA(b_h[n], a_h[m], acc[n][m]);
        }
    }
    // ---- epilogue ----
    if (isV) {
        const int hd = (n0 - 2 * CC) / 64 + wc;
#pragma unroll
        for (int n = 0; n < 4; ++n)
#pragma unroll
            for (int m = 0; m < 4; ++m)
#pragma unroll
                for (int r = 0; r < 4; ++r) {
                    const int dl = n * 16 + lg * 4 + r;
                    const int tok = m0 + wr * 64 + m * 16 + lr;
                    vT[(size_t)(hd * 64 + dl) * 4096 + tok] = f2bf(acc[n][m][r]);
                }
    } else {
        const bool isQ = (n0 < CC);
        const int hd = (isQ ? n0 : n0 - CC) / 64 + wc;
        ushort* ph = isQ ? qh : kh;
        ushort* pl = isQ ? ql : kl;
        float* sg = isQ ? x2g : y2g;
        const float kcv = kcurv[hd];
        const float mxn = (1.0f - PROJ_EPSF) / sqrtf(kcv);
        const float mxn2 = mxn * mxn;
#pragma unroll
        for (int m = 0; m < 4; ++m)
#pragma unroll
            for (int r = 0; r < 4; ++r) {
                float s = 0.f;
#pragma unroll
                for (int n = 0; n < 4; ++n) s = fmaf(acc[m][n][r], acc[m][n][r], s);
                s += __shfl_xor(s, 1);
                s += __shfl_xor(s, 2);
                s += __shfl_xor(s, 4);
                s += __shfl_xor(s, 8);
                float scale = 1.0f, x2v = s;
                if (s > mxn2) {
                    scale = mxn * __builtin_amdgcn_rcpf(sqrtf(s));
                    x2v = s * scale * scale;
                }
                const int tok = m0 + wr * 64 + m * 16 + lg * 4 + r;
                const size_t rowb = (size_t)tok * CC + (isQ ? n0 : n0 - CC) + wc * 64;
#pragma unroll
                for (int n = 0; n < 4; ++n) {
                    const float v = acc[m][n][r] * scale;
                    const ushort hb = f2bf(v);
                    ph[rowb + n * 16 + lr] = hb;
                    pl[rowb + n * 16 + lr] = f2bf(v - bf2f(hb));
                }
                if (lr == 0)
                    sg[(size_t)((tok >> 10) * HH + hd) * TT + (tok & 1023)] = x2v;
            }
    }
}

// ---------------- LDS-staged 2-phase fused hyperbolic attention (R10) ----------------
__global__ __launch_bounds__(128) void hyp_attn(
        const ushort* __restrict__ qh, const ushort* __restrict__ ql,
        const ushort* __restrict__ kh, const ushort* __restrict__ kl,
        const ushort* __restrict__ vT, const float* __restrict__ x2g,
        const float* __restrict__ y2g, const float* __restrict__ kcurv,
        ushort* __restrict__ yh, ushort* __restrict__ yl) {
    const int ib = (int)blockIdx.x;          // 0..1535
    const int xcd = ib & 7, t = ib >> 3;     // t 0..191 per XCD
    const int tcr = t / 12;                  // 0..15, tile-count rank (big first)
    const int which = t - tcr * 12;
    const int g32 = (15 - tcr) * 2 + (which & 1);   // 32-row group 0..31
    const int bh = (which >> 1) * 8 + xcd;   // bh%8 == XCD id
    const int b = bh / HH, h = bh - b * HH;
    const int tid = threadIdx.x, lane = tid & 63, wv = tid >> 6;   // wv 0..1
    const int lr = lane & 15, lg = lane >> 4;
    const int rg = g32 * 2 + wv;             // 16-row group
    const int rgq = g32 >> 1;                // last key-tile index (uniform)

    __shared__ char ldsK[2][16384];          // [buf][hi 8KB | lo 8KB]
    __shared__ char ldsV[8192];              // [dim][key] swizzled
    __shared__ ushort wtb[2][16 * 72];
    ushort* wtw = wtb[wv];

    const float kc = kcurv[h];
    const float sk = sqrtf(kc);
    const float distc = LN2F / sk;
    const float d2c = distc * distc;
    const float twokc = 2.0f * kc;
    const float cA = 1.0f - ATANH_EPSF;

    const size_t qrb = (size_t)(b * TT + rg * 16 + lr) * CC + h * 64 + lg * 8;
    const bf16x8 qH0 = *(const bf16x8*)(qh + qrb), qH1 = *(const bf16x8*)(qh + qrb + 32);
    const bf16x8 qL0 = *(const bf16x8*)(ql + qrb), qL1 = *(const bf16x8*)(ql + qrb + 32);
    const float4 x2v = *(const float4*)&x2g[(size_t)bh * TT + rg * 16 + lg * 4];
    const float x2a[4] = { x2v.x, x2v.y, x2v.z, x2v.w };
    float kx2[4], Bc[4], Bc2[4];
#pragma unroll
    for (int r = 0; r < 4; ++r) {
        kx2[r] = kc * x2a[r];
        Bc[r] = 1.0f - kx2[r];
        Bc2[r] = Bc[r] * Bc[r];
    }

    const int srow8 = lane >> 3;
    const int sgrp = (lane & 7) ^ (srow8 & 7);
    const int so0 = ((lg ^ (lr & 7)) << 4);
    const int so1 = (((4 + lg) ^ (lr & 7)) << 4);
    const int lro = lr << 7;

#define STAGE_K(BUF, J0)                                                          \
    { _Pragma("unroll") for (int c4 = 0; c4 < 4; ++c4) {                          \
        const int c = wv * 4 + c4;                                                \
        const size_t gsrc = (size_t)(b * TT + (J0) + c * 8 + srow8) * CC + h * 64 + sgrp * 8; \
        gl_lds16(kh + gsrc, (char*)(BUF) + c * 1024);                             \
        gl_lds16(kl + gsrc, (char*)(BUF) + 8192 + c * 1024);                      \
    } }
#define STAGE_V(J0)                                                               \
    { _Pragma("unroll") for (int c4 = 0; c4 < 4; ++c4) {                          \
        const int c = wv * 4 + c4;                                                \
        gl_lds16(vT + (size_t)(h * 64 + c * 8 + srow8) * 4096 + b * TT + (J0) + sgrp * 8, \
                 ldsV + c * 1024);                                                \
    } }

#define TRANSF(NN, SA, Y2R)                                                        \
    {                                                                              \
        const float ky2 = kc * (Y2R);                                              \
        const float p1 = 1.0f + ky2;                                               \
        const int jg = j0 + NN * 16 + lr;                                          \
        _Pragma("unroll") for (int r = 0; r < 4; ++r) {                            \
            const float xy = SA[r];                                                \
            const float t2 = twokc * xy;                                           \
            const float Aa = p1 - t2;                                              \
            const float dn = fmaxf(fmaf(kx2[r], ky2, 1.0f) - t2, MIN_NORMF);       \
            const float ABxy = Aa * (Bc[r] * xy);                                  \
            const float c1 = fmaf(Bc2[r], (Y2R), -2.0f * ABxy);                    \
            const float num2 = fmaf(Aa * Aa, x2a[r], c1);                          \
            const float s = sqrtf(fmaxf(num2, MIN_NORMF));                         \
            const float sm = fminf(sk * s, cA * dn);                               \
            const float L = __builtin_amdgcn_logf((dn + sm) *                      \
                                __builtin_amdgcn_rcpf(dn - sm));                   \
            float w = __builtin_amdgcn_rcpf(fmaf(L * L, d2c, WEI_EPSF));           \
            if (mk && (jg > rg * 16 + lg * 4 + r)) w = 0.0f;                       \
            wtw[(lg * 4 + r) * 72 + NN * 16 + lr] = f2bf(w);                       \
            wsum[r] += w;                                                          \
        }                                                                          \
    }

    f32x4 pv[4] = {};
    float wsum[4] = {};

    STAGE_K(ldsK[0], 0)
    asm volatile("s_waitcnt vmcnt(0)" ::: "memory");
    __syncthreads();

    int cur = 0;
    for (int jt = 0; jt <= rgq; ++jt) {
        const int j0 = jt * 64;
        const bool mk = (jt == rgq);
        if (jt < rgq) STAGE_K(ldsK[cur ^ 1], j0 + 64)
        STAGE_V(j0)
        const size_t y2b = (size_t)bh * TT + j0 + lr;
        const float y2n[4] = { y2g[y2b], y2g[y2b + 16], y2g[y2b + 32], y2g[y2b + 48] };
        __builtin_amdgcn_s_setprio(1);
        f32x4 sacc[4] = {};
#pragma unroll
        for (int n = 0; n < 4; ++n) {
            const char* p = ldsK[cur] + n * 2048 + lro;
            bf16x8 h0 = *(const bf16x8*)(p + so0);
            bf16x8 h1 = *(const bf16x8*)(p + so1);
            bf16x8 l0 = *(const bf16x8*)(p + 8192 + so0);
            bf16x8 l1 = *(const bf16x8*)(p + 8192 + so1);
            sacc[n] = MFMA(qH0, h0, sacc[n]);
            sacc[n] = MFMA(qH0, l0, sacc[n]);
            sacc[n] = MFMA(qL0, h0, sacc[n]);
            sacc[n] = MFMA(qH1, h1, sacc[n]);
            sacc[n] = MFMA(qH1, l1, sacc[n]);
            sacc[n] = MFMA(qL1, h1, sacc[n]);
        }
        TRANSF(0, sacc[0], y2n[0])
        TRANSF(1, sacc[1], y2n[1])
        TRANSF(2, sacc[2], y2n[2])
        TRANSF(3, sacc[3], y2n[3])
        __builtin_amdgcn_s_setprio(0);
        asm volatile("s_waitcnt vmcnt(0)" ::: "memory");
        __syncthreads();
        __builtin_amdgcn_s_setprio(1);
        bf16x8 pw0 = *(const bf16x8*)&wtw[lr * 72 + lg * 8];
        bf16x8 pw1 = *(const bf16x8*)&wtw[lr * 72 + 32 + lg * 8];
#pragma unroll
        for (int n = 0; n < 4; ++n) {
            const char* p = ldsV + n * 2048 + lro;
            bf16x8 v0 = *(const bf16x8*)(p + so0);
            bf16x8 v1 = *(const bf16x8*)(p + so1);
            pv[n] = MFMA(pw0, v0, pv[n]);
            pv[n] = MFMA(pw1, v1, pv[n]);
        }
        __builtin_amdgcn_s_setprio(0);
        __syncthreads();
        cur ^= 1;
    }

    float den[4];
#pragma unroll
    for (int r = 0; r < 4; ++r) {
        float s = wsum[r];
        s += __shfl_xor(s, 1);
        s += __shfl_xor(s, 2);
        s += __shfl_xor(s, 4);
        s += __shfl_xor(s, 8);
        den[r] = s;
    }
#pragma unroll
    for (int r = 0; r < 4; ++r) {
        const float iv = __builtin_amdgcn_rcpf(den[r]);
        const size_t rowb = (size_t)(b * TT + rg * 16 + lg * 4 + r) * CC + h * 64;
#pragma unroll
        for (int n = 0; n < 4; ++n) {
            const float val = pv[n][r] * iv;
            const ushort hb = f2bf(val);
            yh[rowb + n * 16 + lr] = hb;
            yl[rowb + n * 16 + lr] = f2bf(val - bf2f(hb));
        }
    }
#undef TRANSF
#undef STAGE_K
#undef STAGE_V
}

// ---------------- output GEMM: pure gl_lds staging, 64x64 tiles ----------------
// grid (64 m, 12 n) m-fastest.  All 4 operand planes pre-split bf16 -> zero
// register round-trip: stage -> vmcnt(0) -> barrier -> MFMA.
__global__ __launch_bounds__(256) void gemm_out(const ushort* __restrict__ Ahp,
                                                const ushort* __restrict__ Alp,
                                                const ushort* __restrict__ Wh,
                                                const ushort* __restrict__ Wl,
                                                float* __restrict__ C) {
    __shared__ ushort Ah[32 * 64], Al[32 * 64], Bh[32 * 64], Bl[32 * 64]; // 4 KB each
    const int tid = threadIdx.x, lane = tid & 63, wv = tid >> 6;
    const int wr = wv >> 1, wc = wv & 1, lr = lane & 15, lg = lane >> 4;
    const int m0 = blockIdx.x * 64, n0 = blockIdx.y * 64;

    // staging: wave wv = call wv per plane; lane -> (packed row, swizzled slot)
    const int sp = 8 * wv + (lane >> 3);
    const int sg = (lane & 7) ^ (sp & 7);
    const int srow = 2 * sp + (sg >> 2);
    const int scol = (sg & 3) * 8;
    const size_t asrc = (size_t)(m0 + srow) * CC + scol;
    const size_t bsrc = (size_t)(n0 + srow) * CC + scol;
    // read constants
    const int goff = (((4 * (lr & 1) + lg) ^ ((lr >> 1) & 7)) << 4);
    const int pa = wr * 16 + (lr >> 1);
    const int pb = wc * 16 + (lr >> 1);

    f32x4 acc[2][2] = {};

    for (int kk = 0; kk < CC; kk += 32) {
        __syncthreads();
        gl_lds16(Ahp + asrc + kk, (char*)Ah + wv * 1024);
        gl_lds16(Alp + asrc + kk, (char*)Al + wv * 1024);
        gl_lds16(Wh + bsrc + kk, (char*)Bh + wv * 1024);
        gl_lds16(Wl + bsrc + kk, (char*)Bl + wv * 1024);
        asm volatile("s_waitcnt vmcnt(0)" ::: "memory");
        __syncthreads();
        bf16x8 a_h[2], a_l[2];
#pragma unroll
        for (int m = 0; m < 2; ++m) {
            const int off = (pa + m * 8) * 128 + goff;
            a_h[m] = *(const bf16x8*)((char*)Ah + off);
            a_l[m] = *(const bf16x8*)((char*)Al + off);
        }
#pragma unroll
        for (int n = 0; n < 2; ++n) {
            const int off = (pb + n * 8) * 128 + goff;
            bf16x8 b_h = *(const bf16x8*)((char*)Bh + off);
            bf16x8 b_l = *(const bf16x8*)((char*)Bl + off);
#pragma unroll
            for (int m = 0; m < 2; ++m) {
                acc[m][n] = MFMA(a_h[m], b_h, acc[m][n]);
                acc[m][n] = MFMA(a_h[m], b_l, acc[m][n]);
                acc[m][n] = MFMA(a_l[m], b_h, acc[m][n]);
            }
        }
    }
#pragma unroll
    for (int m = 0; m < 2; ++m)
#pragma unroll
        for (int n = 0; n < 2; ++n)
#pragma unroll
            for (int r = 0; r < 4; ++r)
                C[(size_t)(m0 + wr * 32 + m * 16 + lg * 4 + r) * CC + n0 + wc * 32 + n * 16 + lr] =
                    acc[m][n][r];
}

extern "C" void kernel_launch(void* const* d_in, const int* in_sizes, int n_in,
                              void* d_out, int out_size, void* d_ws, size_t ws_size,
                              hipStream_t stream) {
    const float* x     = (const float*)d_in[0];
    const float* Wqkv  = (const float*)d_in[1];
    const float* Wproj = (const float*)d_in[2];
    const float* kcurv = (const float*)d_in[3];
    float* out = (float*)d_out;

    const size_t PL = (size_t)4096 * CC;          // 3,145,728 elems
    char* w = (char*)d_ws;
    // region A (12.58 MB): Wqkv hi/lo planes during gemm_qkv; yh/yl after attn
    ushort* Wqh = (ushort*)w;                     // 3.54 MB
    ushort* Wql = Wqh + (size_t)2304 * CC;        // 3.54 MB
    ushort* yh  = (ushort*)w;                     // 6.29 MB (reuse)
    ushort* yl  = yh + PL;                        // 6.29 MB
    ushort* qh  = (ushort*)(w + 2 * PL * 2);      // planes: 5 x 6.29 MB
    ushort* ql  = qh + PL;
    ushort* kh  = ql + PL;
    ushort* kl  = kh + PL;
    ushort* vT  = kl + PL;                        // [12][64][4096]
    ushort* Wph = vT + PL;                        // 1.18 MB
    ushort* Wpl = Wph + (size_t)CC * CC;          // 1.18 MB
    float* x2g  = (float*)(Wpl + (size_t)CC * CC);   // [4][12][1024]
    float* y2g  = x2g + 48 * TT;
    // total: 46,792,704 B (proven available)

    wprep<<<2304 * CC / 4 / 256, 256, 0, stream>>>(Wqkv, Wqh, Wql, 2304 * CC / 4);
    wprep<<<CC * CC / 4 / 256, 256, 0, stream>>>(Wproj, Wph, Wpl, CC * CC / 4);
    gemm_qkv<<<dim3(32, 18), 256, 0, stream>>>(x, Wqh, Wql, kcurv,
                                               qh, ql, kh, kl, vT, x2g, y2g);
    hyp_attn<<<1536, 128, 0, stream>>>(qh, ql, kh, kl, vT, x2g, y2g, kcurv, yh, yl);
    gemm_out<<<dim3(64, 12), 256, 0, stream>>>(yh, yl, Wph, Wpl, out);
}

// Round 12
// 143.326 us; speedup vs baseline: 1.8896x; 1.0892x over previous
//
#include <hip/hip_runtime.h>
#include <hip/hip_bf16.h>
#include <math.h>

#define PROJ_EPSF 0.004f
#define MIN_NORMF 1e-15f
#define ATANH_EPSF 1e-5f
#define WEI_EPSF 1e-3f
#define LN2F 0.69314718055994531f

#define TT 1024
#define CC 768
#define HH 12
#define BBATCH 4

typedef unsigned long long ull;
typedef __attribute__((ext_vector_type(4))) float f32x4;
typedef __attribute__((ext_vector_type(8))) short bf16x8;

#define MFMA(a, b, c) __builtin_amdgcn_mfma_f32_16x16x32_bf16(a, b, c, 0, 0, 0)

static __device__ __forceinline__ uint cvtpk(float a, float b) {
    uint r;
    asm("v_cvt_pk_bf16_f32 %0, %1, %2" : "=v"(r) : "v"(a), "v"(b));
    return r;
}
static __device__ __forceinline__ ushort f2bf(float f) {
    uint u = __float_as_uint(f);
    u += 0x7fffu + ((u >> 16) & 1u);
    return (ushort)(u >> 16);
}
static __device__ __forceinline__ float bf2f(ushort h) {
    return __uint_as_float(((uint)h) << 16);
}
static __device__ __forceinline__ void split4(const float4& f, ull& hp, ull& lp) {
    uint h01 = cvtpk(f.x, f.y), h23 = cvtpk(f.z, f.w);
    float r0 = f.x - __uint_as_float(h01 << 16);
    float r1 = f.y - __uint_as_float(h01 & 0xffff0000u);
    float r2 = f.z - __uint_as_float(h23 << 16);
    float r3 = f.w - __uint_as_float(h23 & 0xffff0000u);
    uint l01 = cvtpk(r0, r1), l23 = cvtpk(r2, r3);
    hp = ((ull)h23 << 32) | h01;
    lp = ((ull)l23 << 32) | l01;
}
union pk16 { bf16x8 v; ull u[2]; };
static __device__ __forceinline__ void gl_lds16(const void* g, void* l) {
    __builtin_amdgcn_global_load_lds(
        (const __attribute__((address_space(1))) unsigned int*)g,
        (__attribute__((address_space(3))) unsigned int*)l, 16, 0, 0);
}

// ---------------- prep: f32 -> bf16 hi/lo planes ----------------
__global__ __launch_bounds__(256) void wprep(const float* __restrict__ W,
                                             ushort* __restrict__ Wh,
                                             ushort* __restrict__ Wl, int n4) {
    int i = blockIdx.x * 256 + threadIdx.x;
    if (i < n4) {
        float4 f = ((const float4*)W)[i];
        ull hp, lp;
        split4(f, hp, lp);
        ((ull*)Wh)[i] = hp;
        ((ull*)Wl)[i] = lp;
    }
}

// ---------------- fused QKV GEMM + projection + layout (R11, proven) ----------------
__global__ __launch_bounds__(256) void gemm_qkv(
        const float* __restrict__ x, const ushort* __restrict__ Wh,
        const ushort* __restrict__ Wl, const float* __restrict__ kcurv,
        ushort* __restrict__ qh, ushort* __restrict__ ql,
        ushort* __restrict__ kh, ushort* __restrict__ kl,
        ushort* __restrict__ vT, float* __restrict__ x2g,
        float* __restrict__ y2g) {
    __shared__ ushort Ah[64 * 64], Al[64 * 64], Bh[64 * 64], Bl[64 * 64];
    const int tid = threadIdx.x, lane = tid & 63, wv = tid >> 6;
    const int wr = wv >> 1, wc = wv & 1, lr = lane & 15, lg = lane >> 4;
    const int m0 = blockIdx.x * 128, n0 = blockIdx.y * 128;
    const bool isV = (n0 >= 2 * CC);

    const int arow = tid >> 1, akh = tid & 1;
    const float* Ap = x + (size_t)(m0 + arow) * CC + akh * 16;
    const int ap_ = arow >> 1;
    const int ag0 = 4 * (arow & 1) + 2 * akh;
    const int aoff0 = ap_ * 128 + ((ag0 ^ (ap_ & 7)) << 4);
    const int aoff1 = ap_ * 128 + (((ag0 + 1) ^ (ap_ & 7)) << 4);
    const int c0 = 2 * wv, c1 = 2 * wv + 1;
    const int p0 = 8 * c0 + (lane >> 3), q0 = (lane & 7) ^ (p0 & 7);
    const int p1 = 8 * c1 + (lane >> 3), q1 = (lane & 7) ^ (p1 & 7);
    const size_t bs0 = (size_t)(n0 + 2 * p0 + (q0 >> 2)) * CC + (q0 & 3) * 8;
    const size_t bs1 = (size_t)(n0 + 2 * p1 + (q1 >> 2)) * CC + (q1 & 3) * 8;
    const int goff = (((4 * (lr & 1) + lg) ^ ((lr >> 1) & 7)) << 4);
    const int pa = wr * 32 + (lr >> 1);
    const int pb = wc * 32 + (lr >> 1);

    f32x4 acc[4][4] = {};
    float4 av[4];
#pragma unroll
    for (int q = 0; q < 4; ++q) av[q] = *(const float4*)(Ap + 4 * q);

    for (int kk = 0; kk < CC; kk += 32) {
        __syncthreads();
        pk16 h, l;
        split4(av[0], h.u[0], l.u[0]);
        split4(av[1], h.u[1], l.u[1]);
        *(bf16x8*)((char*)Ah + aoff0) = h.v;
        if (!isV) *(bf16x8*)((char*)Al + aoff0) = l.v;
        split4(av[2], h.u[0], l.u[0]);
        split4(av[3], h.u[1], l.u[1]);
        *(bf16x8*)((char*)Ah + aoff1) = h.v;
        if (!isV) *(bf16x8*)((char*)Al + aoff1) = l.v;
        gl_lds16(Wh + bs0 + kk, (char*)Bh + c0 * 1024);
        gl_lds16(Wh + bs1 + kk, (char*)Bh + c1 * 1024);
        if (!isV) {
            gl_lds16(Wl + bs0 + kk, (char*)Bl + c0 * 1024);
            gl_lds16(Wl + bs1 + kk, (char*)Bl + c1 * 1024);
        }
        asm volatile("s_waitcnt vmcnt(0)" ::: "memory");
        __syncthreads();
        if (kk + 32 < CC)
#pragma unroll
            for (int q = 0; q < 4; ++q)
                av[q] = *(const float4*)(Ap + kk + 32 + 4 * q);
        if (!isV) {
            bf16x8 a_h[4], a_l[4];
#pragma unroll
            for (int m = 0; m < 4; ++m) {
                const int off = (pa + m * 8) * 128 + goff;
                a_h[m] = *(const bf16x8*)((char*)Ah + off);
                a_l[m] = *(const bf16x8*)((char*)Al + off);
            }
#pragma unroll
            for (int n = 0; n < 4; ++n) {
                const int off = (pb + n * 8) * 128 + goff;
                bf16x8 b_h = *(const bf16x8*)((char*)Bh + off);
                bf16x8 b_l = *(const bf16x8*)((char*)Bl + off);
#pragma unroll
                for (int m = 0; m < 4; ++m) {
                    acc[m][n] = MFMA(a_h[m], b_h, acc[m][n]);
                    acc[m][n] = MFMA(a_h[m], b_l, acc[m][n]);
                    acc[m][n] = MFMA(a_l[m], b_h, acc[m][n]);
                }
            }
        } else {
            bf16x8 a_h[4], b_h[4];
#pragma unroll
            for (int m = 0; m < 4; ++m)
                a_h[m] = *(const bf16x8*)((char*)Ah + (pa + m * 8) * 128 + goff);
#pragma unroll
            for (int n = 0; n < 4; ++n)
                b_h[n] = *(const bf16x8*)((char*)Bh + (pb + n * 8) * 128 + goff);
#pragma unroll
            for (int n = 0; n < 4; ++n)
#pragma unroll
                for (int m = 0; m < 4; ++m)
                    acc[n][m] = MFMA(b_h[n], a_h[m], acc[n][m]);
        }
    }
    if (isV) {
        const int hd = (n0 - 2 * CC) / 64 + wc;
#pragma unroll
        for (int n = 0; n < 4; ++n)
#pragma unroll
            for (int m = 0; m < 4; ++m)
#pragma unroll
                for (int r = 0; r < 4; ++r) {
                    const int dl = n * 16 + lg * 4 + r;
                    const int tok = m0 + wr * 64 + m * 16 + lr;
                    vT[(size_t)(hd * 64 + dl) * 4096 + tok] = f2bf(acc[n][m][r]);
                }
    } else {
        const bool isQ = (n0 < CC);
        const int hd = (isQ ? n0 : n0 - CC) / 64 + wc;
        ushort* ph = isQ ? qh : kh;
        ushort* pl = isQ ? ql : kl;
        float* sg = isQ ? x2g : y2g;
        const float kcv = kcurv[hd];
        const float mxn = (1.0f - PROJ_EPSF) / sqrtf(kcv);
        const float mxn2 = mxn * mxn;
#pragma unroll
        for (int m = 0; m < 4; ++m)
#pragma unroll
            for (int r = 0; r < 4; ++r) {
                float s = 0.f;
#pragma unroll
                for (int n = 0; n < 4; ++n) s = fmaf(acc[m][n][r], acc[m][n][r], s);
                s += __shfl_xor(s, 1);
                s += __shfl_xor(s, 2);
                s += __shfl_xor(s, 4);
                s += __shfl_xor(s, 8);
                float scale = 1.0f, x2v = s;
                if (s > mxn2) {
                    scale = mxn * __builtin_amdgcn_rcpf(sqrtf(s));
                    x2v = s * scale * scale;
                }
                const int tok = m0 + wr * 64 + m * 16 + lg * 4 + r;
                const size_t rowb = (size_t)tok * CC + (isQ ? n0 : n0 - CC) + wc * 64;
#pragma unroll
                for (int n = 0; n < 4; ++n) {
                    const float v = acc[m][n][r] * scale;
                    const ushort hb = f2bf(v);
                    ph[rowb + n * 16 + lr] = hb;
                    pl[rowb + n * 16 + lr] = f2bf(v - bf2f(hb));
                }
                if (lr == 0)
                    sg[(size_t)((tok >> 10) * HH + hd) * TT + (tok & 1023)] = x2v;
            }
    }
}

// ---------------- 4-wave LDS-staged attention, counted vmcnt, raw barriers ----------------
// Block = 64 q-rows (4 waves); all waves march the same key tiles 0..g64.
// V staged before K(t+1) so PV waits only vmcnt(4) (K stays in flight).
__global__ __launch_bounds__(256) void hyp_attn(
        const ushort* __restrict__ qh, const ushort* __restrict__ ql,
        const ushort* __restrict__ kh, const ushort* __restrict__ kl,
        const ushort* __restrict__ vT, const float* __restrict__ x2g,
        const float* __restrict__ y2g, const float* __restrict__ kcurv,
        ushort* __restrict__ yh, ushort* __restrict__ yl) {
    const int ib = (int)blockIdx.x;          // 0..767
    const int xcd = ib & 7, t = ib >> 3;     // t 0..95 per XCD
    const int tcr = t / 6;                   // 0..15, big-first rank
    const int which = t - tcr * 6;
    const int g64 = 15 - tcr;                // 64-row group, 16 tiles max
    const int bh = which * 8 + xcd;          // bh%8 == XCD id
    const int b = bh / HH, h = bh - b * HH;
    const int tid = threadIdx.x, lane = tid & 63, wv = tid >> 6;   // wv 0..3
    const int lr = lane & 15, lg = lane >> 4;
    const int rg = g64 * 4 + wv;             // 16-row group
    const int rgq = g64;                     // last key-tile (uniform all waves)

    __shared__ char ldsK[2][16384];          // [buf][hi 8KB | lo 8KB]
    __shared__ char ldsV[8192];
    __shared__ ushort wtb[4][16 * 72];
    ushort* wtw = wtb[wv];

    const float kc = kcurv[h];
    const float sk = sqrtf(kc);
    const float distc = LN2F / sk;
    const float d2c = distc * distc;
    const float twokc = 2.0f * kc;
    const float cA = 1.0f - ATANH_EPSF;

    const size_t qrb = (size_t)(b * TT + rg * 16 + lr) * CC + h * 64 + lg * 8;
    const bf16x8 qH0 = *(const bf16x8*)(qh + qrb), qH1 = *(const bf16x8*)(qh + qrb + 32);
    const bf16x8 qL0 = *(const bf16x8*)(ql + qrb), qL1 = *(const bf16x8*)(ql + qrb + 32);
    const float4 x2v = *(const float4*)&x2g[(size_t)bh * TT + rg * 16 + lg * 4];
    const float x2a[4] = { x2v.x, x2v.y, x2v.z, x2v.w };
    float kx2[4], Bc[4], Bc2[4];
#pragma unroll
    for (int r = 0; r < 4; ++r) {
        kx2[r] = kc * x2a[r];
        Bc[r] = 1.0f - kx2[r];
        Bc2[r] = Bc[r] * Bc[r];
    }

    const int srow8 = lane >> 3;
    const int sgrp = (lane & 7) ^ (srow8 & 7);
    const int so0 = ((lg ^ (lr & 7)) << 4);
    const int so1 = (((4 + lg) ^ (lr & 7)) << 4);
    const int lro = lr << 7;

    // wave wv covers calls c = wv*2 + {0,1}
#define STAGE_K(BUF, J0)                                                          \
    { _Pragma("unroll") for (int c4 = 0; c4 < 2; ++c4) {                          \
        const int c = wv * 2 + c4;                                                \
        const size_t gsrc = (size_t)(b * TT + (J0) + c * 8 + srow8) * CC + h * 64 + sgrp * 8; \
        gl_lds16(kh + gsrc, (char*)(BUF) + c * 1024);                             \
        gl_lds16(kl + gsrc, (char*)(BUF) + 8192 + c * 1024);                      \
    } }
#define STAGE_V(J0)                                                               \
    { _Pragma("unroll") for (int c4 = 0; c4 < 2; ++c4) {                          \
        const int c = wv * 2 + c4;                                                \
        gl_lds16(vT + (size_t)(h * 64 + c * 8 + srow8) * 4096 + b * TT + (J0) + sgrp * 8, \
                 ldsV + c * 1024);                                                \
    } }

#define TRANSF(NN, SA, Y2R)                                                        \
    {                                                                              \
        const float ky2 = kc * (Y2R);                                              \
        const float p1 = 1.0f + ky2;                                               \
        const int jg = j0 + NN * 16 + lr;                                          \
        _Pragma("unroll") for (int r = 0; r < 4; ++r) {                            \
            const float xy = SA[r];                                                \
            const float t2 = twokc * xy;                                           \
            const float Aa = p1 - t2;                                              \
            const float dn = fmaxf(fmaf(kx2[r], ky2, 1.0f) - t2, MIN_NORMF);       \
            const float ABxy = Aa * (Bc[r] * xy);                                  \
            const float c1 = fmaf(Bc2[r], (Y2R), -2.0f * ABxy);                    \
            const float num2 = fmaf(Aa * Aa, x2a[r], c1);                          \
            const float s = sqrtf(fmaxf(num2, MIN_NORMF));                         \
            const float sm = fminf(sk * s, cA * dn);                               \
            const float L = __builtin_amdgcn_logf((dn + sm) *                      \
                                __builtin_amdgcn_rcpf(dn - sm));                   \
            float w = __builtin_amdgcn_rcpf(fmaf(L * L, d2c, WEI_EPSF));           \
            if (mk && (jg > rg * 16 + lg * 4 + r)) w = 0.0f;                       \
            wtw[(lg * 4 + r) * 72 + NN * 16 + lr] = f2bf(w);                       \
            wsum[r] += w;                                                          \
        }                                                                          \
    }

    f32x4 pv[4] = {};
    float wsum[4] = {};

    STAGE_K(ldsK[0], 0)   // prologue; landing enforced by iter-0 vmcnt

    int cur = 0;
    for (int jt = 0; jt <= rgq; ++jt) {
        const int j0 = jt * 64;
        const bool mk = (jt == rgq);
        STAGE_V(j0)                               // 2 calls (oldest of new)
        if (jt < rgq) {
            STAGE_K(ldsK[cur ^ 1], j0 + 64)       // 4 calls
            asm volatile("s_waitcnt vmcnt(6)" ::: "memory");   // K(t) landed
        } else {
            asm volatile("s_waitcnt vmcnt(2)" ::: "memory");
        }
        __builtin_amdgcn_s_barrier();
        __builtin_amdgcn_sched_barrier(0);
        const size_t y2b = (size_t)bh * TT + j0 + lr;
        const float y2n[4] = { y2g[y2b], y2g[y2b + 16], y2g[y2b + 32], y2g[y2b + 48] };
        __builtin_amdgcn_s_setprio(1);
        f32x4 sacc[4] = {};
#pragma unroll
        for (int n = 0; n < 4; ++n) {
            const char* p = ldsK[cur] + n * 2048 + lro;
            bf16x8 h0 = *(const bf16x8*)(p + so0);
            bf16x8 h1 = *(const bf16x8*)(p + so1);
            bf16x8 l0 = *(const bf16x8*)(p + 8192 + so0);
            bf16x8 l1 = *(const bf16x8*)(p + 8192 + so1);
            sacc[n] = MFMA(qH0, h0, sacc[n]);
            sacc[n] = MFMA(qH0, l0, sacc[n]);
            sacc[n] = MFMA(qL0, h0, sacc[n]);
            sacc[n] = MFMA(qH1, h1, sacc[n]);
            sacc[n] = MFMA(qH1, l1, sacc[n]);
            sacc[n] = MFMA(qL1, h1, sacc[n]);
        }
        TRANSF(0, sacc[0], y2n[0])
        TRANSF(1, sacc[1], y2n[1])
        TRANSF(2, sacc[2], y2n[2])
        TRANSF(3, sacc[3], y2n[3])
        __builtin_amdgcn_s_setprio(0);
        if (jt < rgq)
            asm volatile("s_waitcnt vmcnt(4)" ::: "memory");   // V landed, K(t+1) flying
        else
            asm volatile("s_waitcnt vmcnt(0)" ::: "memory");
        __builtin_amdgcn_s_barrier();
        __builtin_amdgcn_sched_barrier(0);
        __builtin_amdgcn_s_setprio(1);
        bf16x8 pw0 = *(const bf16x8*)&wtw[lr * 72 + lg * 8];
        bf16x8 pw1 = *(const bf16x8*)&wtw[lr * 72 + 32 + lg * 8];
#pragma unroll
        for (int n = 0; n < 4; ++n) {
            const char* p = ldsV + n * 2048 + lro;
            bf16x8 v0 = *(const bf16x8*)(p + so0);
            bf16x8 v1 = *(const bf16x8*)(p + so1);
            pv[n] = MFMA(pw0, v0, pv[n]);
            pv[n] = MFMA(pw1, v1, pv[n]);
        }
        __builtin_amdgcn_s_setprio(0);
        __builtin_amdgcn_s_barrier();             // protect ldsV for next stage
        cur ^= 1;
    }

    float den[4];
#pragma unroll
    for (int r = 0; r < 4; ++r) {
        float s = wsum[r];
        s += __shfl_xor(s, 1);
        s += __shfl_xor(s, 2);
        s += __shfl_xor(s, 4);
        s += __shfl_xor(s, 8);
        den[r] = s;
    }
#pragma unroll
    for (int r = 0; r < 4; ++r) {
        const float iv = __builtin_amdgcn_rcpf(den[r]);
        const size_t rowb = (size_t)(b * TT + rg * 16 + lg * 4 + r) * CC + h * 64;
#pragma unroll
        for (int n = 0; n < 4; ++n) {
            const float val = pv[n][r] * iv;
            const ushort hb = f2bf(val);
            yh[rowb + n * 16 + lr] = hb;
            yl[rowb + n * 16 + lr] = f2bf(val - bf2f(hb));
        }
    }
#undef TRANSF
#undef STAGE_K
#undef STAGE_V
}

// ---------------- output GEMM: dbuf gl_lds staging, counted vmcnt ----------------
__global__ __launch_bounds__(256) void gemm_out(const ushort* __restrict__ Ahp,
                                                const ushort* __restrict__ Alp,
                                                const ushort* __restrict__ Wh,
                                                const ushort* __restrict__ Wl,
                                                float* __restrict__ C) {
    __shared__ ushort Ah[2][32 * 64], Al[2][32 * 64], Bh[2][32 * 64], Bl[2][32 * 64];
    const int tid = threadIdx.x, lane = tid & 63, wv = tid >> 6;
    const int wr = wv >> 1, wc = wv & 1, lr = lane & 15, lg = lane >> 4;
    const int m0 = blockIdx.x * 64, n0 = blockIdx.y * 64;

    const int sp = 8 * wv + (lane >> 3);
    const int sg = (lane & 7) ^ (sp & 7);
    const int srow = 2 * sp + (sg >> 2);
    const int scol = (sg & 3) * 8;
    const size_t asrc = (size_t)(m0 + srow) * CC + scol;
    const size_t bsrc = (size_t)(n0 + srow) * CC + scol;
    const int goff = (((4 * (lr & 1) + lg) ^ ((lr >> 1) & 7)) << 4);
    const int pa = wr * 16 + (lr >> 1);
    const int pb = wc * 16 + (lr >> 1);

    f32x4 acc[2][2] = {};

#define STAGE_O(BUF, KK)                                                          \
    gl_lds16(Ahp + asrc + (KK), (char*)Ah[BUF] + wv * 1024);                      \
    gl_lds16(Alp + asrc + (KK), (char*)Al[BUF] + wv * 1024);                      \
    gl_lds16(Wh + bsrc + (KK), (char*)Bh[BUF] + wv * 1024);                       \
    gl_lds16(Wl + bsrc + (KK), (char*)Bl[BUF] + wv * 1024);

    STAGE_O(0, 0)
    int cur = 0;
    for (int kk = 0; kk < CC; kk += 32) {
        if (kk + 32 < CC) {
            STAGE_O(cur ^ 1, kk + 32)
            asm volatile("s_waitcnt vmcnt(4)" ::: "memory");
        } else {
            asm volatile("s_waitcnt vmcnt(0)" ::: "memory");
        }
        __builtin_amdgcn_s_barrier();
        __builtin_amdgcn_sched_barrier(0);
        bf16x8 a_h[2], a_l[2];
#pragma unroll
        for (int m = 0; m < 2; ++m) {
            const int off = (pa + m * 8) * 128 + goff;
            a_h[m] = *(const bf16x8*)((char*)Ah[cur] + off);
            a_l[m] = *(const bf16x8*)((char*)Al[cur] + off);
        }
#pragma unroll
        for (int n = 0; n < 2; ++n) {
            const int off = (pb + n * 8) * 128 + goff;
            bf16x8 b_h = *(const bf16x8*)((char*)Bh[cur] + off);
            bf16x8 b_l = *(const bf16x8*)((char*)Bl[cur] + off);
#pragma unroll
            for (int m = 0; m < 2; ++m) {
                acc[m][n] = MFMA(a_h[m], b_h, acc[m][n]);
                acc[m][n] = MFMA(a_h[m], b_l, acc[m][n]);
                acc[m][n] = MFMA(a_l[m], b_h, acc[m][n]);
            }
        }
        __builtin_amdgcn_s_barrier();
        cur ^= 1;
    }
#undef STAGE_O
#pragma unroll
    for (int m = 0; m < 2; ++m)
#pragma unroll
        for (int n = 0; n < 2; ++n)
#pragma unroll
            for (int r = 0; r < 4; ++r)
                C[(size_t)(m0 + wr * 32 + m * 16 + lg * 4 + r) * CC + n0 + wc * 32 + n * 16 + lr] =
                    acc[m][n][r];
}

extern "C" void kernel_launch(void* const* d_in, const int* in_sizes, int n_in,
                              void* d_out, int out_size, void* d_ws, size_t ws_size,
                              hipStream_t stream) {
    const float* x     = (const float*)d_in[0];
    const float* Wqkv  = (const float*)d_in[1];
    const float* Wproj = (const float*)d_in[2];
    const float* kcurv = (const float*)d_in[3];
    float* out = (float*)d_out;

    const size_t PL = (size_t)4096 * CC;
    char* w = (char*)d_ws;
    ushort* Wqh = (ushort*)w;
    ushort* Wql = Wqh + (size_t)2304 * CC;
    ushort* yh  = (ushort*)w;                     // reuse after gemm_qkv
    ushort* yl  = yh + PL;
    ushort* qh  = (ushort*)(w + 2 * PL * 2);
    ushort* ql  = qh + PL;
    ushort* kh  = ql + PL;
    ushort* kl  = kh + PL;
    ushort* vT  = kl + PL;
    ushort* Wph = vT + PL;
    ushort* Wpl = Wph + (size_t)CC * CC;
    float* x2g  = (float*)(Wpl + (size_t)CC * CC);
    float* y2g  = x2g + 48 * TT;

    wprep<<<2304 * CC / 4 / 256, 256, 0, stream>>>(Wqkv, Wqh, Wql, 2304 * CC / 4);
    wprep<<<CC * CC / 4 / 256, 256, 0, stream>>>(Wproj, Wph, Wpl, CC * CC / 4);
    gemm_qkv<<<dim3(32, 18), 256, 0, stream>>>(x, Wqh, Wql, kcurv,
                                               qh, ql, kh, kl, vT, x2g, y2g);
    hyp_attn<<<768, 256, 0, stream>>>(qh, ql, kh, kl, vT, x2g, y2g, kcurv, yh, yl);
    gemm_out<<<dim3(64, 12), 256, 0, stream>>>(yh, yl, Wph, Wpl, out);
}

// Round 13
// 142.708 us; speedup vs baseline: 1.8978x; 1.0043x over previous
//
#include <hip/hip_runtime.h>
#include <hip/hip_bf16.h>
#include <math.h>

#define PROJ_EPSF 0.004f
#define MIN_NORMF 1e-15f
#define ATANH_EPSF 1e-5f
#define WEI_EPSF 1e-3f
#define LN2F 0.69314718055994531f

#define TT 1024
#define CC 768
#define HH 12
#define BBATCH 4

typedef unsigned long long ull;
typedef __attribute__((ext_vector_type(4))) float f32x4;
typedef __attribute__((ext_vector_type(8))) short bf16x8;

#define MFMA(a, b, c) __builtin_amdgcn_mfma_f32_16x16x32_bf16(a, b, c, 0, 0, 0)

static __device__ __forceinline__ uint cvtpk(float a, float b) {
    uint r;
    asm("v_cvt_pk_bf16_f32 %0, %1, %2" : "=v"(r) : "v"(a), "v"(b));
    return r;
}
static __device__ __forceinline__ ushort f2bf(float f) {
    uint u = __float_as_uint(f);
    u += 0x7fffu + ((u >> 16) & 1u);
    return (ushort)(u >> 16);
}
static __device__ __forceinline__ float bf2f(ushort h) {
    return __uint_as_float(((uint)h) << 16);
}
static __device__ __forceinline__ void split4(const float4& f, ull& hp, ull& lp) {
    uint h01 = cvtpk(f.x, f.y), h23 = cvtpk(f.z, f.w);
    float r0 = f.x - __uint_as_float(h01 << 16);
    float r1 = f.y - __uint_as_float(h01 & 0xffff0000u);
    float r2 = f.z - __uint_as_float(h23 << 16);
    float r3 = f.w - __uint_as_float(h23 & 0xffff0000u);
    uint l01 = cvtpk(r0, r1), l23 = cvtpk(r2, r3);
    hp = ((ull)h23 << 32) | h01;
    lp = ((ull)l23 << 32) | l01;
}
union pk16 { bf16x8 v; ull u[2]; };
static __device__ __forceinline__ void gl_lds16(const void* g, void* l) {
    __builtin_amdgcn_global_load_lds(
        (const __attribute__((address_space(1))) unsigned int*)g,
        (__attribute__((address_space(3))) unsigned int*)l, 16, 0, 0);
}

// ---------------- prep: f32 -> bf16 hi/lo planes ----------------
__global__ __launch_bounds__(256) void wprep(const float* __restrict__ W,
                                             ushort* __restrict__ Wh,
                                             ushort* __restrict__ Wl, int n4) {
    int i = blockIdx.x * 256 + threadIdx.x;
    if (i < n4) {
        float4 f = ((const float4*)W)[i];
        ull hp, lp;
        split4(f, hp, lp);
        ((ull*)Wh)[i] = hp;
        ((ull*)Wl)[i] = lp;
    }
}

// ---------------- fused QKV GEMM: dbuf staging, counted vmcnt, 1 barrier/iter ----------------
__global__ __launch_bounds__(256) void gemm_qkv(
        const float* __restrict__ x, const ushort* __restrict__ Wh,
        const ushort* __restrict__ Wl, const float* __restrict__ kcurv,
        ushort* __restrict__ qh, ushort* __restrict__ ql,
        ushort* __restrict__ kh, ushort* __restrict__ kl,
        ushort* __restrict__ vT, float* __restrict__ x2g,
        float* __restrict__ y2g) {
    __shared__ ushort Ah[2][64 * 64], Al[2][64 * 64], Bh[2][64 * 64], Bl[2][64 * 64];
    const int tid = threadIdx.x, lane = tid & 63, wv = tid >> 6;
    const int wr = wv >> 1, wc = wv & 1, lr = lane & 15, lg = lane >> 4;
    const int m0 = blockIdx.x * 128, n0 = blockIdx.y * 128;
    const bool isV = (n0 >= 2 * CC);

    const int arow = tid >> 1, akh = tid & 1;
    const float* Ap = x + (size_t)(m0 + arow) * CC + akh * 16;
    const int ap_ = arow >> 1;
    const int ag0 = 4 * (arow & 1) + 2 * akh;
    const int aoff0 = ap_ * 128 + ((ag0 ^ (ap_ & 7)) << 4);
    const int aoff1 = ap_ * 128 + (((ag0 + 1) ^ (ap_ & 7)) << 4);
    const int c0 = 2 * wv, c1 = 2 * wv + 1;
    const int p0 = 8 * c0 + (lane >> 3), q0 = (lane & 7) ^ (p0 & 7);
    const int p1 = 8 * c1 + (lane >> 3), q1 = (lane & 7) ^ (p1 & 7);
    const size_t bs0 = (size_t)(n0 + 2 * p0 + (q0 >> 2)) * CC + (q0 & 3) * 8;
    const size_t bs1 = (size_t)(n0 + 2 * p1 + (q1 >> 2)) * CC + (q1 & 3) * 8;
    const int goff = (((4 * (lr & 1) + lg) ^ ((lr >> 1) & 7)) << 4);
    const int pa = wr * 32 + (lr >> 1);
    const int pb = wc * 32 + (lr >> 1);

    f32x4 acc[4][4] = {};
    float4 av[4];

#define STAGE_B(BUF, KK)                                                          \
    gl_lds16(Wh + bs0 + (KK), (char*)Bh[BUF] + c0 * 1024);                        \
    gl_lds16(Wh + bs1 + (KK), (char*)Bh[BUF] + c1 * 1024);                        \
    if (!isV) {                                                                   \
        gl_lds16(Wl + bs0 + (KK), (char*)Bl[BUF] + c0 * 1024);                    \
        gl_lds16(Wl + bs1 + (KK), (char*)Bl[BUF] + c1 * 1024);                    \
    }
#define SPLIT_A(BUF)                                                              \
    {                                                                             \
        pk16 h_, l_;                                                              \
        split4(av[0], h_.u[0], l_.u[0]);                                          \
        split4(av[1], h_.u[1], l_.u[1]);                                          \
        *(bf16x8*)((char*)Ah[BUF] + aoff0) = h_.v;                                \
        if (!isV) *(bf16x8*)((char*)Al[BUF] + aoff0) = l_.v;                      \
        split4(av[2], h_.u[0], l_.u[0]);                                          \
        split4(av[3], h_.u[1], l_.u[1]);                                          \
        *(bf16x8*)((char*)Ah[BUF] + aoff1) = h_.v;                                \
        if (!isV) *(bf16x8*)((char*)Al[BUF] + aoff1) = l_.v;                      \
    }
#define LOAD_A(KK)                                                                \
    { _Pragma("unroll") for (int q = 0; q < 4; ++q)                               \
        av[q] = *(const float4*)(Ap + (KK) + 4 * q); }

    // ---- prologue: A(0)+B(0) -> buf0, A(1) in regs, B(0) landed ----
    LOAD_A(0)
    STAGE_B(0, 0)
    SPLIT_A(0)          // compiler waits A(0) loads (B(0) keeps flying)
    LOAD_A(32)
    asm volatile("s_waitcnt vmcnt(4) lgkmcnt(0)" ::: "memory");   // B(0) landed
    __builtin_amdgcn_s_barrier();
    __builtin_amdgcn_sched_barrier(0);

    int cur = 0;
    for (int kk = 0; kk < CC; kk += 32) {
        const bool notLast = (kk + 32 < CC);
        if (notLast) {
            STAGE_B(cur ^ 1, kk + 32)
            SPLIT_A(cur ^ 1)                     // A(k+1) regs -> buf^1
            if (kk + 64 < CC) LOAD_A(kk + 64)    // A(k+2) -> regs (flying)
            __builtin_amdgcn_sched_barrier(0);
        }
        // ---- MFMA from buf[cur] ----
        if (!isV) {
            bf16x8 a_h[4], a_l[4];
#pragma unroll
            for (int m = 0; m < 4; ++m) {
                const int off = (pa + m * 8) * 128 + goff;
                a_h[m] = *(const bf16x8*)((char*)Ah[cur] + off);
                a_l[m] = *(const bf16x8*)((char*)Al[cur] + off);
            }
#pragma unroll
            for (int n = 0; n < 4; ++n) {
                const int off = (pb + n * 8) * 128 + goff;
                bf16x8 b_h = *(const bf16x8*)((char*)Bh[cur] + off);
                bf16x8 b_l = *(const bf16x8*)((char*)Bl[cur] + off);
#pragma unroll
                for (int m = 0; m < 4; ++m) {
                    acc[m][n] = MFMA(a_h[m], b_h, acc[m][n]);
                    acc[m][n] = MFMA(a_h[m], b_l, acc[m][n]);
                    acc[m][n] = MFMA(a_l[m], b_h, acc[m][n]);
                }
            }
        } else {
            bf16x8 a_h[4], b_h[4];
#pragma unroll
            for (int m = 0; m < 4; ++m)
                a_h[m] = *(const bf16x8*)((char*)Ah[cur] + (pa + m * 8) * 128 + goff);
#pragma unroll
            for (int n = 0; n < 4; ++n)
                b_h[n] = *(const bf16x8*)((char*)Bh[cur] + (pb + n * 8) * 128 + goff);
#pragma unroll
            for (int n = 0; n < 4; ++n)
#pragma unroll
                for (int m = 0; m < 4; ++m)
                    acc[n][m] = MFMA(b_h[n], a_h[m], acc[n][m]);
        }
        // ---- bottom: B(k+1) must land; A(k+2) reg-loads may fly ----
        if (notLast) {
            if (kk + 64 < CC)
                asm volatile("s_waitcnt vmcnt(4) lgkmcnt(0)" ::: "memory");
            else
                asm volatile("s_waitcnt vmcnt(0) lgkmcnt(0)" ::: "memory");
            __builtin_amdgcn_s_barrier();
            __builtin_amdgcn_sched_barrier(0);
        }
        cur ^= 1;
    }
#undef STAGE_B
#undef SPLIT_A
#undef LOAD_A

    // ---- epilogue ----
    if (isV) {
        const int hd = (n0 - 2 * CC) / 64 + wc;
#pragma unroll
        for (int n = 0; n < 4; ++n)
#pragma unroll
            for (int m = 0; m < 4; ++m)
#pragma unroll
                for (int r = 0; r < 4; ++r) {
                    const int dl = n * 16 + lg * 4 + r;
                    const int tok = m0 + wr * 64 + m * 16 + lr;
                    vT[(size_t)(hd * 64 + dl) * 4096 + tok] = f2bf(acc[n][m][r]);
                }
    } else {
        const bool isQ = (n0 < CC);
        const int hd = (isQ ? n0 : n0 - CC) / 64 + wc;
        ushort* ph = isQ ? qh : kh;
        ushort* pl = isQ ? ql : kl;
        float* sg = isQ ? x2g : y2g;
        const float kcv = kcurv[hd];
        const float mxn = (1.0f - PROJ_EPSF) / sqrtf(kcv);
        const float mxn2 = mxn * mxn;
#pragma unroll
        for (int m = 0; m < 4; ++m)
#pragma unroll
            for (int r = 0; r < 4; ++r) {
                float s = 0.f;
#pragma unroll
                for (int n = 0; n < 4; ++n) s = fmaf(acc[m][n][r], acc[m][n][r], s);
                s += __shfl_xor(s, 1);
                s += __shfl_xor(s, 2);
                s += __shfl_xor(s, 4);
                s += __shfl_xor(s, 8);
                float scale = 1.0f, x2v = s;
                if (s > mxn2) {
                    scale = mxn * __builtin_amdgcn_rcpf(sqrtf(s));
                    x2v = s * scale * scale;
                }
                const int tok = m0 + wr * 64 + m * 16 + lg * 4 + r;
                const size_t rowb = (size_t)tok * CC + (isQ ? n0 : n0 - CC) + wc * 64;
#pragma unroll
                for (int n = 0; n < 4; ++n) {
                    const float v = acc[m][n][r] * scale;
                    const ushort hb = f2bf(v);
                    ph[rowb + n * 16 + lr] = hb;
                    pl[rowb + n * 16 + lr] = f2bf(v - bf2f(hb));
                }
                if (lr == 0)
                    sg[(size_t)((tok >> 10) * HH + hd) * TT + (tok & 1023)] = x2v;
            }
    }
}

// ---------------- 4-wave LDS-staged attention, counted vmcnt, raw barriers (R12) ----------------
__global__ __launch_bounds__(256) void hyp_attn(
        const ushort* __restrict__ qh, const ushort* __restrict__ ql,
        const ushort* __restrict__ kh, const ushort* __restrict__ kl,
        const ushort* __restrict__ vT, const float* __restrict__ x2g,
        const float* __restrict__ y2g, const float* __restrict__ kcurv,
        ushort* __restrict__ yh, ushort* __restrict__ yl) {
    const int ib = (int)blockIdx.x;          // 0..767
    const int xcd = ib & 7, t = ib >> 3;     // t 0..95 per XCD
    const int tcr = t / 6;                   // 0..15, big-first rank
    const int which = t - tcr * 6;
    const int g64 = 15 - tcr;                // 64-row group
    const int bh = which * 8 + xcd;          // bh%8 == XCD id
    const int b = bh / HH, h = bh - b * HH;
    const int tid = threadIdx.x, lane = tid & 63, wv = tid >> 6;   // wv 0..3
    const int lr = lane & 15, lg = lane >> 4;
    const int rg = g64 * 4 + wv;
    const int rgq = g64;

    __shared__ char ldsK[2][16384];
    __shared__ char ldsV[8192];
    __shared__ ushort wtb[4][16 * 72];
    ushort* wtw = wtb[wv];

    const float kc = kcurv[h];
    const float sk = sqrtf(kc);
    const float distc = LN2F / sk;
    const float d2c = distc * distc;
    const float twokc = 2.0f * kc;
    const float cA = 1.0f - ATANH_EPSF;

    const size_t qrb = (size_t)(b * TT + rg * 16 + lr) * CC + h * 64 + lg * 8;
    const bf16x8 qH0 = *(const bf16x8*)(qh + qrb), qH1 = *(const bf16x8*)(qh + qrb + 32);
    const bf16x8 qL0 = *(const bf16x8*)(ql + qrb), qL1 = *(const bf16x8*)(ql + qrb + 32);
    const float4 x2v = *(const float4*)&x2g[(size_t)bh * TT + rg * 16 + lg * 4];
    const float x2a[4] = { x2v.x, x2v.y, x2v.z, x2v.w };
    float kx2[4], Bc[4], Bc2[4];
#pragma unroll
    for (int r = 0; r < 4; ++r) {
        kx2[r] = kc * x2a[r];
        Bc[r] = 1.0f - kx2[r];
        Bc2[r] = Bc[r] * Bc[r];
    }

    const int srow8 = lane >> 3;
    const int sgrp = (lane & 7) ^ (srow8 & 7);
    const int so0 = ((lg ^ (lr & 7)) << 4);
    const int so1 = (((4 + lg) ^ (lr & 7)) << 4);
    const int lro = lr << 7;

#define STAGE_K(BUF, J0)                                                          \
    { _Pragma("unroll") for (int c4 = 0; c4 < 2; ++c4) {                          \
        const int c = wv * 2 + c4;                                                \
        const size_t gsrc = (size_t)(b * TT + (J0) + c * 8 + srow8) * CC + h * 64 + sgrp * 8; \
        gl_lds16(kh + gsrc, (char*)(BUF) + c * 1024);                             \
        gl_lds16(kl + gsrc, (char*)(BUF) + 8192 + c * 1024);                      \
    } }
#define STAGE_V(J0)                                                               \
    { _Pragma("unroll") for (int c4 = 0; c4 < 2; ++c4) {                          \
        const int c = wv * 2 + c4;                                                \
        gl_lds16(vT + (size_t)(h * 64 + c * 8 + srow8) * 4096 + b * TT + (J0) + sgrp * 8, \
                 ldsV + c * 1024);                                                \
    } }

#define TRANSF(NN, SA, Y2R)                                                        \
    {                                                                              \
        const float ky2 = kc * (Y2R);                                              \
        const float p1 = 1.0f + ky2;                                               \
        const int jg = j0 + NN * 16 + lr;                                          \
        _Pragma("unroll") for (int r = 0; r < 4; ++r) {                            \
            const float xy = SA[r];                                                \
            const float t2 = twokc * xy;                                           \
            const float Aa = p1 - t2;                                              \
            const float dn = fmaxf(fmaf(kx2[r], ky2, 1.0f) - t2, MIN_NORMF);       \
            const float ABxy = Aa * (Bc[r] * xy);                                  \
            const float c1 = fmaf(Bc2[r], (Y2R), -2.0f * ABxy);                    \
            const float num2 = fmaf(Aa * Aa, x2a[r], c1);                          \
            const float s = sqrtf(fmaxf(num2, MIN_NORMF));                         \
            const float sm = fminf(sk * s, cA * dn);                               \
            const float L = __builtin_amdgcn_logf((dn + sm) *                      \
                                __builtin_amdgcn_rcpf(dn - sm));                   \
            float w = __builtin_amdgcn_rcpf(fmaf(L * L, d2c, WEI_EPSF));           \
            if (mk && (jg > rg * 16 + lg * 4 + r)) w = 0.0f;                       \
            wtw[(lg * 4 + r) * 72 + NN * 16 + lr] = f2bf(w);                       \
            wsum[r] += w;                                                          \
        }                                                                          \
    }

    f32x4 pv[4] = {};
    float wsum[4] = {};

    STAGE_K(ldsK[0], 0)

    int cur = 0;
    for (int jt = 0; jt <= rgq; ++jt) {
        const int j0 = jt * 64;
        const bool mk = (jt == rgq);
        STAGE_V(j0)
        if (jt < rgq) {
            STAGE_K(ldsK[cur ^ 1], j0 + 64)
            asm volatile("s_waitcnt vmcnt(6)" ::: "memory");
        } else {
            asm volatile("s_waitcnt vmcnt(2)" ::: "memory");
        }
        __builtin_amdgcn_s_barrier();
        __builtin_amdgcn_sched_barrier(0);
        const size_t y2b = (size_t)bh * TT + j0 + lr;
        const float y2n[4] = { y2g[y2b], y2g[y2b + 16], y2g[y2b + 32], y2g[y2b + 48] };
        __builtin_amdgcn_s_setprio(1);
        f32x4 sacc[4] = {};
#pragma unroll
        for (int n = 0; n < 4; ++n) {
            const char* p = ldsK[cur] + n * 2048 + lro;
            bf16x8 h0 = *(const bf16x8*)(p + so0);
            bf16x8 h1 = *(const bf16x8*)(p + so1);
            bf16x8 l0 = *(const bf16x8*)(p + 8192 + so0);
            bf16x8 l1 = *(const bf16x8*)(p + 8192 + so1);
            sacc[n] = MFMA(qH0, h0, sacc[n]);
            sacc[n] = MFMA(qH0, l0, sacc[n]);
            sacc[n] = MFMA(qL0, h0, sacc[n]);
            sacc[n] = MFMA(qH1, h1, sacc[n]);
            sacc[n] = MFMA(qH1, l1, sacc[n]);
            sacc[n] = MFMA(qL1, h1, sacc[n]);
        }
        TRANSF(0, sacc[0], y2n[0])
        TRANSF(1, sacc[1], y2n[1])
        TRANSF(2, sacc[2], y2n[2])
        TRANSF(3, sacc[3], y2n[3])
        __builtin_amdgcn_s_setprio(0);
        if (jt < rgq)
            asm volatile("s_waitcnt vmcnt(4)" ::: "memory");
        else
            asm volatile("s_waitcnt vmcnt(0)" ::: "memory");
        __builtin_amdgcn_s_barrier();
        __builtin_amdgcn_sched_barrier(0);
        __builtin_amdgcn_s_setprio(1);
        bf16x8 pw0 = *(const bf16x8*)&wtw[lr * 72 + lg * 8];
        bf16x8 pw1 = *(const bf16x8*)&wtw[lr * 72 + 32 + lg * 8];
#pragma unroll
        for (int n = 0; n < 4; ++n) {
            const char* p = ldsV + n * 2048 + lro;
            bf16x8 v0 = *(const bf16x8*)(p + so0);
            bf16x8 v1 = *(const bf16x8*)(p + so1);
            pv[n] = MFMA(pw0, v0, pv[n]);
            pv[n] = MFMA(pw1, v1, pv[n]);
        }
        __builtin_amdgcn_s_setprio(0);
        __builtin_amdgcn_s_barrier();
        cur ^= 1;
    }

    float den[4];
#pragma unroll
    for (int r = 0; r < 4; ++r) {
        float s = wsum[r];
        s += __shfl_xor(s, 1);
        s += __shfl_xor(s, 2);
        s += __shfl_xor(s, 4);
        s += __shfl_xor(s, 8);
        den[r] = s;
    }
#pragma unroll
    for (int r = 0; r < 4; ++r) {
        const float iv = __builtin_amdgcn_rcpf(den[r]);
        const size_t rowb = (size_t)(b * TT + rg * 16 + lg * 4 + r) * CC + h * 64;
#pragma unroll
        for (int n = 0; n < 4; ++n) {
            const float val = pv[n][r] * iv;
            const ushort hb = f2bf(val);
            yh[rowb + n * 16 + lr] = hb;
            yl[rowb + n * 16 + lr] = f2bf(val - bf2f(hb));
        }
    }
#undef TRANSF
#undef STAGE_K
#undef STAGE_V
}

// ---------------- output GEMM: dbuf gl_lds staging, counted vmcnt (R12) ----------------
__global__ __launch_bounds__(256) void gemm_out(const ushort* __restrict__ Ahp,
                                                const ushort* __restrict__ Alp,
                                                const ushort* __restrict__ Wh,
                                                const ushort* __restrict__ Wl,
                                                float* __restrict__ C) {
    __shared__ ushort Ah[2][32 * 64], Al[2][32 * 64], Bh[2][32 * 64], Bl[2][32 * 64];
    const int tid = threadIdx.x, lane = tid & 63, wv = tid >> 6;
    const int wr = wv >> 1, wc = wv & 1, lr = lane & 15, lg = lane >> 4;
    const int m0 = blockIdx.x * 64, n0 = blockIdx.y * 64;

    const int sp = 8 * wv + (lane >> 3);
    const int sg = (lane & 7) ^ (sp & 7);
    const int srow = 2 * sp + (sg >> 2);
    const int scol = (sg & 3) * 8;
    const size_t asrc = (size_t)(m0 + srow) * CC + scol;
    const size_t bsrc = (size_t)(n0 + srow) * CC + scol;
    const int goff = (((4 * (lr & 1) + lg) ^ ((lr >> 1) & 7)) << 4);
    const int pa = wr * 16 + (lr >> 1);
    const int pb = wc * 16 + (lr >> 1);

    f32x4 acc[2][2] = {};

#define STAGE_O(BUF, KK)                                                          \
    gl_lds16(Ahp + asrc + (KK), (char*)Ah[BUF] + wv * 1024);                      \
    gl_lds16(Alp + asrc + (KK), (char*)Al[BUF] + wv * 1024);                      \
    gl_lds16(Wh + bsrc + (KK), (char*)Bh[BUF] + wv * 1024);                       \
    gl_lds16(Wl + bsrc + (KK), (char*)Bl[BUF] + wv * 1024);

    STAGE_O(0, 0)
    int cur = 0;
    for (int kk = 0; kk < CC; kk += 32) {
        if (kk + 32 < CC) {
            STAGE_O(cur ^ 1, kk + 32)
            asm volatile("s_waitcnt vmcnt(4)" ::: "memory");
        } else {
            asm volatile("s_waitcnt vmcnt(0)" ::: "memory");
        }
        __builtin_amdgcn_s_barrier();
        __builtin_amdgcn_sched_barrier(0);
        bf16x8 a_h[2], a_l[2];
#pragma unroll
        for (int m = 0; m < 2; ++m) {
            const int off = (pa + m * 8) * 128 + goff;
            a_h[m] = *(const bf16x8*)((char*)Ah[cur] + off);
            a_l[m] = *(const bf16x8*)((char*)Al[cur] + off);
        }
#pragma unroll
        for (int n = 0; n < 2; ++n) {
            const int off = (pb + n * 8) * 128 + goff;
            bf16x8 b_h = *(const bf16x8*)((char*)Bh[cur] + off);
            bf16x8 b_l = *(const bf16x8*)((char*)Bl[cur] + off);
#pragma unroll
            for (int m = 0; m < 2; ++m) {
                acc[m][n] = MFMA(a_h[m], b_h, acc[m][n]);
                acc[m][n] = MFMA(a_h[m], b_l, acc[m][n]);
                acc[m][n] = MFMA(a_l[m], b_h, acc[m][n]);
            }
        }
        __builtin_amdgcn_s_barrier();
        cur ^= 1;
    }
#undef STAGE_O
#pragma unroll
    for (int m = 0; m < 2; ++m)
#pragma unroll
        for (int n = 0; n < 2; ++n)
#pragma unroll
            for (int r = 0; r < 4; ++r)
                C[(size_t)(m0 + wr * 32 + m * 16 + lg * 4 + r) * CC + n0 + wc * 32 + n * 16 + lr] =
                    acc[m][n][r];
}

extern "C" void kernel_launch(void* const* d_in, const int* in_sizes, int n_in,
                              void* d_out, int out_size, void* d_ws, size_t ws_size,
                              hipStream_t stream) {
    const float* x     = (const float*)d_in[0];
    const float* Wqkv  = (const float*)d_in[1];
    const float* Wproj = (const float*)d_in[2];
    const float* kcurv = (const float*)d_in[3];
    float* out = (float*)d_out;

    const size_t PL = (size_t)4096 * CC;
    char* w = (char*)d_ws;
    ushort* Wqh = (ushort*)w;
    ushort* Wql = Wqh + (size_t)2304 * CC;
    ushort* yh  = (ushort*)w;                     // reuse after gemm_qkv
    ushort* yl  = yh + PL;
    ushort* qh  = (ushort*)(w + 2 * PL * 2);
    ushort* ql  = qh + PL;
    ushort* kh  = ql + PL;
    ushort* kl  = kh + PL;
    ushort* vT  = kl + PL;
    ushort* Wph = vT + PL;
    ushort* Wpl = Wph + (size_t)CC * CC;
    float* x2g  = (float*)(Wpl + (size_t)CC * CC);
    float* y2g  = x2g + 48 * TT;

    wprep<<<2304 * CC / 4 / 256, 256, 0, stream>>>(Wqkv, Wqh, Wql, 2304 * CC / 4);
    wprep<<<CC * CC / 4 / 256, 256, 0, stream>>>(Wproj, Wph, Wpl, CC * CC / 4);
    gemm_qkv<<<dim3(32, 18), 256, 0, stream>>>(x, Wqh, Wql, kcurv,
                                               qh, ql, kh, kl, vT, x2g, y2g);
    hyp_attn<<<768, 256, 0, stream>>>(qh, ql, kh, kl, vT, x2g, y2g, kcurv, yh, yl);
    gemm_out<<<dim3(64, 12), 256, 0, stream>>>(yh, yl, Wph, Wpl, out);
}